// Round 6
// baseline (670.763 us; speedup 1.0000x reference)
//
#include <hip/hip_runtime.h>

#define NU 50000
#define NP 50000
#define NN 100000
#define NE 600000
#define H  128
#define O  16

// ---------------------------------------------------------------- init / degree
__global__ void k_init(int* __restrict__ cnt, int* __restrict__ cursor, int n) {
    int i = blockIdx.x * blockDim.x + threadIdx.x;
    if (i < n) { cnt[i] = 0; cursor[i] = 0; }
}

__global__ void k_count(const int* __restrict__ dst, int* __restrict__ cnt, int E) {
    int e = blockIdx.x * blockDim.x + threadIdx.x;
    if (e < E) atomicAdd(&cnt[dst[e]], 1);
}

__global__ void k_dinv(const int* __restrict__ cnt, float* __restrict__ dinv, int n) {
    int i = blockIdx.x * blockDim.x + threadIdx.x;
    if (i < n) dinv[i] = rsqrtf((float)(cnt[i] + 1));   // +1 self-loop; deg>=1 always
}

// ---------------------------------------------------------------- exclusive scan (3-pass)
#define SCAN_TPB 256
#define SCAN_VPT 4
#define SCAN_CHUNK (SCAN_TPB * SCAN_VPT)   // 1024

__global__ void k_scan1(const int* __restrict__ in, int* __restrict__ out,
                        int* __restrict__ bsums, int n) {
    __shared__ int sh[SCAN_TPB];
    int t = threadIdx.x, b = blockIdx.x;
    int base = b * SCAN_CHUNK + t * SCAN_VPT;
    int v[SCAN_VPT]; int s = 0;
#pragma unroll
    for (int i = 0; i < SCAN_VPT; i++) {
        int idx = base + i;
        v[i] = (idx < n) ? in[idx] : 0;
        s += v[i];
    }
    sh[t] = s; __syncthreads();
    for (int off = 1; off < SCAN_TPB; off <<= 1) {
        int x = (t >= off) ? sh[t - off] : 0;
        __syncthreads();
        sh[t] += x;
        __syncthreads();
    }
    int run = (t > 0) ? sh[t - 1] : 0;          // exclusive prefix of this thread
    if (t == SCAN_TPB - 1) bsums[b] = sh[t];    // block total
#pragma unroll
    for (int i = 0; i < SCAN_VPT; i++) {
        int idx = base + i;
        if (idx < n) out[idx] = run;
        run += v[i];
    }
}

__global__ void k_scan2(int* __restrict__ bsums, int nb, int* __restrict__ total) {
    __shared__ int sh[128];
    int t = threadIdx.x;
    int v = (t < nb) ? bsums[t] : 0;
    sh[t] = v; __syncthreads();
    for (int off = 1; off < 128; off <<= 1) {
        int x = (t >= off) ? sh[t - off] : 0;
        __syncthreads();
        sh[t] += x;
        __syncthreads();
    }
    if (t < nb) bsums[t] = sh[t] - v;           // exclusive
    if (t == 127) *total = sh[127];
}

__global__ void k_scan3(int* __restrict__ out, const int* __restrict__ bsums, int n) {
    int idx = blockIdx.x * blockDim.x + threadIdx.x;
    if (idx < n) out[idx] += bsums[idx / SCAN_CHUNK];
}

// ---------------------------------------------------------------- CSR fill (counting sort by dst)
__global__ void k_fill(const int* __restrict__ src, const int* __restrict__ dst,
                       const int* __restrict__ offs, int* __restrict__ cursor,
                       const float* __restrict__ dinv,
                       int2* __restrict__ epack, int E) {
    int e = blockIdx.x * blockDim.x + threadIdx.x;
    if (e < E) {
        int s = src[e], d = dst[e];
        int p = offs[d] + atomicAdd(&cursor[d], 1);
        int2 r;
        r.x = s;
        r.y = __float_as_int(dinv[s] * dinv[d]);
        epack[p] = r;
    }
}

// ---------------------------------------------------------------- GEMM v4
// C[M,128] = A[M,K] @ W[K,128] (+bias). 256 threads, 128x128 tile, 8x8 reg tile.
// LDS holds ONLY the transposed A-tile (32 KB) -> B fragments are read straight
// from global W: all waves/blocks read the same 32 KB W-chunk (L1-resident,
// same-address lanes coalesce), moving B off the per-CU LDS pipe which was the
// R4/R5 bottleneck (4 ds_read_b128/kk -> 2 broadcast reads/kk).
// 3 blocks/CU (LDS 32KB, VGPR capped by launch_bounds).
template <int K, bool BIAS>
__launch_bounds__(256, 3)
__global__ void k_gemm(const float* __restrict__ A, const float* __restrict__ W,
                       const float* __restrict__ bias, float* __restrict__ Cout,
                       int M, int orow0) {
    __shared__ __align__(16) float As[64][128];

    const int tid = threadIdx.x;
    const int m0  = blockIdx.x * 128;
    const int c4  = (tid & 15) * 4;      // col frag base (and +64)
    const int r0  = (tid >> 4) * 8;      // row frag base

    // A staging: 2 threads per row, each 32 consecutive k
    const int a_lrow = tid >> 1;
    const int a_koff = (tid & 1) * 32;
    const int a_grow = m0 + a_lrow;

    float4 av[8];
    auto load_chunk = [&](int k0) {
        if (a_grow < M) {
            if (k0 + a_koff + 32 <= K) {
                const float* p = &A[(size_t)a_grow * K + k0 + a_koff];
#pragma unroll
                for (int j = 0; j < 8; j++) av[j] = *(const float4*)(p + 4 * j);
            } else {
#pragma unroll
                for (int j = 0; j < 8; j++)
#pragma unroll
                    for (int i = 0; i < 4; i++) {
                        int k = k0 + a_koff + 4 * j + i;
                        ((float*)&av[j])[i] = (k < K) ? A[(size_t)a_grow * K + k] : 0.0f;
                    }
            }
        } else {
#pragma unroll
            for (int j = 0; j < 8; j++) av[j] = make_float4(0.f, 0.f, 0.f, 0.f);
        }
    };
    auto store_chunk = [&]() {
#pragma unroll
        for (int j = 0; j < 8; j++) {
            As[a_koff + 4 * j + 0][a_lrow] = av[j].x;   // bank=row%32, 2-way, free
            As[a_koff + 4 * j + 1][a_lrow] = av[j].y;
            As[a_koff + 4 * j + 2][a_lrow] = av[j].z;
            As[a_koff + 4 * j + 3][a_lrow] = av[j].w;
        }
    };

    float acc[8][8];
    if (BIAS) {
        float4 blo = *(const float4*)&bias[c4];
        float4 bhi = *(const float4*)&bias[64 + c4];
#pragma unroll
        for (int i = 0; i < 8; i++) {
            acc[i][0] = blo.x; acc[i][1] = blo.y; acc[i][2] = blo.z; acc[i][3] = blo.w;
            acc[i][4] = bhi.x; acc[i][5] = bhi.y; acc[i][6] = bhi.z; acc[i][7] = bhi.w;
        }
    } else {
#pragma unroll
        for (int i = 0; i < 8; i++)
#pragma unroll
            for (int j = 0; j < 8; j++) acc[i][j] = 0.0f;
    }

    const int NCH = (K + 63) / 64;
    load_chunk(0);

    for (int ch = 0; ch < NCH; ch++) {
        __syncthreads();
        store_chunk();
        __syncthreads();
        if (ch + 1 < NCH) load_chunk((ch + 1) * 64);   // in flight during compute

        const int k0 = ch * 64;
#pragma unroll 4
        for (int kk = 0; kk < 64; kk++) {
            // clamp protects K=100 tail (As rows are zero there, product = 0)
            const int krow = (K % 64 == 0) ? (k0 + kk) : min(k0 + kk, K - 1);
            float4 b0 = *(const float4*)&W[(size_t)krow * H + c4];       // L1-hot
            float4 b1 = *(const float4*)&W[(size_t)krow * H + 64 + c4];
            float4 a0 = *(const float4*)&As[kk][r0];                     // broadcast
            float4 a1 = *(const float4*)&As[kk][r0 + 4];
            float a[8] = {a0.x, a0.y, a0.z, a0.w, a1.x, a1.y, a1.z, a1.w};
            float b[8] = {b0.x, b0.y, b0.z, b0.w, b1.x, b1.y, b1.z, b1.w};
#pragma unroll
            for (int i = 0; i < 8; i++)
#pragma unroll
                for (int j = 0; j < 8; j++)
                    acc[i][j] = fmaf(a[i], b[j], acc[i][j]);
        }
    }

#pragma unroll
    for (int i = 0; i < 8; i++) {
        int grow = m0 + r0 + i;
        if (grow < M) {
            float4 o0 = make_float4(acc[i][0], acc[i][1], acc[i][2], acc[i][3]);
            float4 o1 = make_float4(acc[i][4], acc[i][5], acc[i][6], acc[i][7]);
            *(float4*)&Cout[(size_t)(orow0 + grow) * H + c4]      = o0;
            *(float4*)&Cout[(size_t)(orow0 + grow) * H + 64 + c4] = o1;
        }
    }
}

// ---------------------------------------------------------------- CSR gather + bias + ReLU
// One WAVE per node: 64 lanes x float2 = 512B row; edge records batch-loaded
// (one int2/lane) then broadcast via readlane; no LDS, no barrier.
__launch_bounds__(256)
__global__ void k_aggregate(const float* __restrict__ y, const int* __restrict__ offs,
                            const int2* __restrict__ epack,
                            const float* __restrict__ dinv, const float* __restrict__ bias,
                            float* __restrict__ out) {
    const int node = blockIdx.x * 4 + (threadIdx.x >> 6);
    const int l    = threadIdx.x & 63;
    const int e0 = offs[node], e1 = offs[node + 1];
    const int deg = e1 - e0;

    const float2* y2 = (const float2*)y;      // row stride = 64 float2
    float2 acc = make_float2(0.f, 0.f);

    for (int base = 0; base < deg; base += 64) {
        const int m = min(64, deg - base);
        int2 pk = (l < m) ? epack[e0 + base + l] : make_int2(0, 0);
#pragma unroll 4
        for (int j = 0; j < m; j++) {
            int   s = __builtin_amdgcn_readlane(pk.x, j);         // uniform
            float w = __int_as_float(__builtin_amdgcn_readlane(pk.y, j));
            float2 v = y2[(size_t)s * 64 + l];                    // 512B row
            acc.x = fmaf(w, v.x, acc.x);
            acc.y = fmaf(w, v.y, acc.y);
        }
    }

    const float  di = dinv[node];
    const float2 sv = y2[(size_t)node * 64 + l];                  // self-loop
    const float2 bv = *(const float2*)&bias[2 * l];
    float rx = fmaf(sv.x, di * di, acc.x) + bv.x;
    float ry = fmaf(sv.y, di * di, acc.y) + bv.y;
    float2 o = make_float2(fmaxf(rx, 0.f), fmaxf(ry, 0.f));
    *((float2*)out + (size_t)node * 64 + l) = o;
}

// ---------------------------------------------------------------- output GEMM [NN,128]@[128,16]
// Full X row-tile (128x128 = 64 KB) transposed in LDS, ONE barrier.
// Thread tile: 8 rows x 1 col; Wo (8 KB) read from global (L1 broadcast).
__launch_bounds__(256, 2)
__global__ void k_out2(const float* __restrict__ X, const float* __restrict__ Wo,
                       const float* __restrict__ bo, float* __restrict__ out, int M) {
    __shared__ float As[128][128];
    const int tid  = threadIdx.x;
    const int m0   = blockIdx.x * 128;
    const int lrow = tid >> 1;
    const int koff = (tid & 1) * 64;
    const int grow = m0 + lrow;

    if (grow < M) {
        const float* p = &X[(size_t)grow * H + koff];
#pragma unroll
        for (int j = 0; j < 16; j++) {
            float4 v = *(const float4*)(p + 4 * j);
            As[koff + 4 * j + 0][lrow] = v.x;
            As[koff + 4 * j + 1][lrow] = v.y;
            As[koff + 4 * j + 2][lrow] = v.z;
            As[koff + 4 * j + 3][lrow] = v.w;
        }
    } else {
#pragma unroll
        for (int j = 0; j < 64; j++) As[koff + j][lrow] = 0.0f;
    }
    __syncthreads();

    const int o  = tid & 15;
    const int r0 = (tid >> 4) * 8;
    float acc[8];
    float bias = bo[o];
#pragma unroll
    for (int i = 0; i < 8; i++) acc[i] = bias;

#pragma unroll 4
    for (int kk = 0; kk < H; kk++) {
        float w  = Wo[kk * O + o];                 // L1-hot broadcast
        float4 a0 = *(const float4*)&As[kk][r0];
        float4 a1 = *(const float4*)&As[kk][r0 + 4];
        acc[0] = fmaf(a0.x, w, acc[0]); acc[1] = fmaf(a0.y, w, acc[1]);
        acc[2] = fmaf(a0.z, w, acc[2]); acc[3] = fmaf(a0.w, w, acc[3]);
        acc[4] = fmaf(a1.x, w, acc[4]); acc[5] = fmaf(a1.y, w, acc[5]);
        acc[6] = fmaf(a1.z, w, acc[6]); acc[7] = fmaf(a1.w, w, acc[7]);
    }
#pragma unroll
    for (int i = 0; i < 8; i++) {
        int r = m0 + r0 + i;
        if (r < M) out[(size_t)r * O + o] = acc[i];
    }
}

// ---------------------------------------------------------------- launch
extern "C" void kernel_launch(void* const* d_in, const int* in_sizes, int n_in,
                              void* d_out, int out_size, void* d_ws, size_t ws_size,
                              hipStream_t stream) {
    const float* user = (const float*)d_in[0];
    const float* prod = (const float*)d_in[1];
    const int*   eidx = (const int*)  d_in[2];
    const int*   edst = eidx + NE;           // edge_index[1]
    const int*   esrc_in = eidx;             // edge_index[0]
    const float* Wu = (const float*)d_in[3];
    const float* bu = (const float*)d_in[4];
    const float* Wp = (const float*)d_in[5];
    const float* bp = (const float*)d_in[6];
    const float* W1 = (const float*)d_in[7];
    const float* b1 = (const float*)d_in[8];
    const float* W2 = (const float*)d_in[9];
    const float* b2 = (const float*)d_in[10];
    const float* W3 = (const float*)d_in[11];
    const float* b3 = (const float*)d_in[12];
    const float* Wo = (const float*)d_in[13];
    const float* bo = (const float*)d_in[14];
    float* out = (float*)d_out;

    char* ws = (char*)d_ws;
    size_t p = 0;
    auto alloc = [&](size_t bytes) -> void* {
        void* r = ws + p;
        p += (bytes + 255) & ~(size_t)255;
        return r;
    };
    float* xA    = (float*)alloc((size_t)NN * H * 4);
    float* xB    = (float*)alloc((size_t)NN * H * 4);
    int*   cnt   = (int*)  alloc((size_t)NN * 4);
    int*   cursor= (int*)  alloc((size_t)NN * 4);
    int*   offs  = (int*)  alloc((size_t)(NN + 1) * 4);
    float* dinv  = (float*)alloc((size_t)NN * 4);
    int2*  epack = (int2*) alloc((size_t)NE * 8);
    int*   bsums = (int*)  alloc(128 * 4);

    const int NBLK = (NN + SCAN_CHUNK - 1) / SCAN_CHUNK;   // 98

    // graph structure (once per call, reused across 3 layers)
    k_init <<<(NN + 255) / 256, 256, 0, stream>>>(cnt, cursor, NN);
    k_count<<<(NE + 255) / 256, 256, 0, stream>>>(edst, cnt, NE);
    k_dinv <<<(NN + 255) / 256, 256, 0, stream>>>(cnt, dinv, NN);
    k_scan1<<<NBLK, SCAN_TPB, 0, stream>>>(cnt, offs, bsums, NN);
    k_scan2<<<1, 128, 0, stream>>>(bsums, NBLK, offs + NN);
    k_scan3<<<(NN + 255) / 256, 256, 0, stream>>>(offs, bsums, NN);
    k_fill <<<(NE + 255) / 256, 256, 0, stream>>>(esrc_in, edst, offs, cursor, dinv,
                                                  epack, NE);

    // input feature transforms -> xA
    k_gemm<64, true>  <<<(NU + 127) / 128, 256, 0, stream>>>(user, Wu, bu, xA, NU, 0);
    k_gemm<100, true> <<<(NP + 127) / 128, 256, 0, stream>>>(prod, Wp, bp, xA, NP, NU);

    // layer 1
    k_gemm<H, false><<<(NN + 127) / 128, 256, 0, stream>>>(xA, W1, nullptr, xB, NN, 0);
    k_aggregate<<<NN / 4, 256, 0, stream>>>(xB, offs, epack, dinv, b1, xA);
    // layer 2
    k_gemm<H, false><<<(NN + 127) / 128, 256, 0, stream>>>(xA, W2, nullptr, xB, NN, 0);
    k_aggregate<<<NN / 4, 256, 0, stream>>>(xB, offs, epack, dinv, b2, xA);
    // layer 3
    k_gemm<H, false><<<(NN + 127) / 128, 256, 0, stream>>>(xA, W3, nullptr, xB, NN, 0);
    k_aggregate<<<NN / 4, 256, 0, stream>>>(xB, offs, epack, dinv, b3, xA);

    // output head
    k_out2<<<(NN + 127) / 128, 256, 0, stream>>>(xA, Wo, bo, out, NN);
}

// Round 7
// 539.822 us; speedup vs baseline: 1.2426x; 1.2426x over previous
//
#include <hip/hip_runtime.h>

#define NU 50000
#define NP 50000
#define NN 100000
#define NE 600000
#define H  128
#define O  16

typedef __attribute__((ext_vector_type(8))) short short8;
typedef __attribute__((ext_vector_type(4))) float f32x4;

// split fp32 into bf16 hi + bf16 lo (RNE); x ≈ hi + lo to ~2^-17 rel
__device__ inline void split_bf16(float x, short& h, short& l) {
    unsigned u  = __float_as_uint(x);
    unsigned hb = (u + 0x7fffu + ((u >> 16) & 1u)) & 0xffff0000u;
    h = (short)(hb >> 16);
    float lo = x - __uint_as_float(hb);
    unsigned ul = __float_as_uint(lo);
    l = (short)((ul + 0x7fffu + ((ul >> 16) & 1u)) >> 16);
}

// ---------------------------------------------------------------- init / degree
__global__ void k_init(int* __restrict__ cnt, int* __restrict__ cursor, int n) {
    int i = blockIdx.x * blockDim.x + threadIdx.x;
    if (i < n) { cnt[i] = 0; cursor[i] = 0; }
}

__global__ void k_count(const int* __restrict__ dst, int* __restrict__ cnt, int E) {
    int e = blockIdx.x * blockDim.x + threadIdx.x;
    if (e < E) atomicAdd(&cnt[dst[e]], 1);
}

__global__ void k_dinv(const int* __restrict__ cnt, float* __restrict__ dinv, int n) {
    int i = blockIdx.x * blockDim.x + threadIdx.x;
    if (i < n) dinv[i] = rsqrtf((float)(cnt[i] + 1));
}

// ---------------------------------------------------------------- exclusive scan
#define SCAN_TPB 256
#define SCAN_VPT 4
#define SCAN_CHUNK (SCAN_TPB * SCAN_VPT)

__global__ void k_scan1(const int* __restrict__ in, int* __restrict__ out,
                        int* __restrict__ bsums, int n) {
    __shared__ int sh[SCAN_TPB];
    int t = threadIdx.x, b = blockIdx.x;
    int base = b * SCAN_CHUNK + t * SCAN_VPT;
    int v[SCAN_VPT]; int s = 0;
#pragma unroll
    for (int i = 0; i < SCAN_VPT; i++) {
        int idx = base + i;
        v[i] = (idx < n) ? in[idx] : 0;
        s += v[i];
    }
    sh[t] = s; __syncthreads();
    for (int off = 1; off < SCAN_TPB; off <<= 1) {
        int x = (t >= off) ? sh[t - off] : 0;
        __syncthreads();
        sh[t] += x;
        __syncthreads();
    }
    int run = (t > 0) ? sh[t - 1] : 0;
    if (t == SCAN_TPB - 1) bsums[b] = sh[t];
#pragma unroll
    for (int i = 0; i < SCAN_VPT; i++) {
        int idx = base + i;
        if (idx < n) out[idx] = run;
        run += v[i];
    }
}

__global__ void k_scan2(int* __restrict__ bsums, int nb, int* __restrict__ total) {
    __shared__ int sh[128];
    int t = threadIdx.x;
    int v = (t < nb) ? bsums[t] : 0;
    sh[t] = v; __syncthreads();
    for (int off = 1; off < 128; off <<= 1) {
        int x = (t >= off) ? sh[t - off] : 0;
        __syncthreads();
        sh[t] += x;
        __syncthreads();
    }
    if (t < nb) bsums[t] = sh[t] - v;
    if (t == 127) *total = sh[127];
}

__global__ void k_scan3(int* __restrict__ out, const int* __restrict__ bsums, int n) {
    int idx = blockIdx.x * blockDim.x + threadIdx.x;
    if (idx < n) out[idx] += bsums[idx / SCAN_CHUNK];
}

// ---------------------------------------------------------------- CSR fill
__global__ void k_fill(const int* __restrict__ src, const int* __restrict__ dst,
                       const int* __restrict__ offs, int* __restrict__ cursor,
                       const float* __restrict__ dinv,
                       int2* __restrict__ epack, int E) {
    int e = blockIdx.x * blockDim.x + threadIdx.x;
    if (e < E) {
        int s = src[e], d = dst[e];
        int p = offs[d] + atomicAdd(&cursor[d], 1);
        int2 r;
        r.x = s;
        r.y = __float_as_int(dinv[s] * dinv[d]);
        epack[p] = r;
    }
}

// ---------------------------------------------------------------- weight prep
// W[K][128] fp32 -> Wt_hi/Wt_lo bf16, TRANSPOSED layout [n][KPAD] (k-contig,
// zero-padded k>=K). Done once per call; makes GEMM B-staging a plain copy.
__global__ void k_wprep(const float* __restrict__ W, short* __restrict__ Wh,
                        short* __restrict__ Wl, int K, int KPAD) {
    int idx = blockIdx.x * blockDim.x + threadIdx.x;   // n*KPAD + k, k fastest
    if (idx >= 128 * KPAD) return;
    int n = idx / KPAD, k = idx - n * KPAD;
    float x = (k < K) ? W[k * H + n] : 0.0f;
    short h, l; split_bf16(x, h, l);
    Wh[idx] = h; Wl[idx] = l;
}

// ---------------------------------------------------------------- MFMA GEMM (split-bf16)
// C[M,128] = A[M,K](fp32) @ W[K,128] (+bias), via 3-term bf16 MFMA:
//   x*w ~= xh*wh + xh*wl + xl*wh   (xh/xl split in-kernel during staging)
// Block: 256 thr = 4 waves (2x2), 128x128 tile; wave = 64x64 = 4x4 MFMA tiles
// of 16x16x32. BK=32 chunks, LDS 32 KB. Frag layouts per m89/m120:
//   A[m=lane&15][k=q*8+j] ; B[k][n=lane&15] k-contig ; D col=lane&15,row=q*4+reg
template <int K, int KPAD, bool BIAS>
__launch_bounds__(256)
__global__ void k_gemm_mx(const float* __restrict__ A, const short* __restrict__ Wh,
                          const short* __restrict__ Wl, const float* __restrict__ bias,
                          float* __restrict__ Cout, int M, int orow0) {
    __shared__ __align__(16) short Xh[128][32], Xl[128][32];
    __shared__ __align__(16) short Bh[128][32], Bl[128][32];

    const int tid  = threadIdx.x;
    const int m0   = blockIdx.x * 128;
    const int wid  = tid >> 6, lane = tid & 63;
    const int wm   = (wid >> 1) * 64, wn = (wid & 1) * 64;
    const int lm   = lane & 15,  q  = lane >> 4;

    const int s_row  = tid >> 1;          // 0..127 (X row / W n-row)
    const int s_half = tid & 1;           // which 16-k half
    const int grow   = m0 + s_row;

    float xv[16];
    uint4 wvh[2], wvl[2];

    auto gload = [&](int k0) {
        const int kb = k0 + s_half * 16;
        if (grow < M && kb + 16 <= K) {
            const float* p = &A[(size_t)grow * K + kb];
#pragma unroll
            for (int j = 0; j < 4; j++) {
                float4 v = *(const float4*)(p + 4 * j);
                xv[4*j] = v.x; xv[4*j+1] = v.y; xv[4*j+2] = v.z; xv[4*j+3] = v.w;
            }
        } else {
#pragma unroll
            for (int j = 0; j < 16; j++) {
                int k = kb + j;
                xv[j] = (grow < M && k < K) ? A[(size_t)grow * K + k] : 0.0f;
            }
        }
        const short* ph = &Wh[s_row * KPAD + kb];
        const short* pl = &Wl[s_row * KPAD + kb];
        wvh[0] = *(const uint4*)ph; wvh[1] = *(const uint4*)(ph + 8);
        wvl[0] = *(const uint4*)pl; wvl[1] = *(const uint4*)(pl + 8);
    };

    auto sstore = [&]() {
        short8 h0, h1, l0, l1;
#pragma unroll
        for (int j = 0; j < 8; j++) {
            short hh, ll;
            split_bf16(xv[j], hh, ll);     h0[j] = hh; l0[j] = ll;
            split_bf16(xv[j + 8], hh, ll); h1[j] = hh; l1[j] = ll;
        }
        *(short8*)&Xh[s_row][s_half * 16]     = h0;
        *(short8*)&Xh[s_row][s_half * 16 + 8] = h1;
        *(short8*)&Xl[s_row][s_half * 16]     = l0;
        *(short8*)&Xl[s_row][s_half * 16 + 8] = l1;
        *(uint4*)&Bh[s_row][s_half * 16]      = wvh[0];
        *(uint4*)&Bh[s_row][s_half * 16 + 8]  = wvh[1];
        *(uint4*)&Bl[s_row][s_half * 16]      = wvl[0];
        *(uint4*)&Bl[s_row][s_half * 16 + 8]  = wvl[1];
    };

    f32x4 acc[4][4];
#pragma unroll
    for (int i = 0; i < 4; i++)
#pragma unroll
        for (int j = 0; j < 4; j++) acc[i][j] = (f32x4)0.0f;

    const int NCH = KPAD / 32;
    gload(0);

    for (int ch = 0; ch < NCH; ch++) {
        __syncthreads();
        sstore();
        __syncthreads();
        if (ch + 1 < NCH) gload((ch + 1) * 32);

        short8 bh[4], bl[4];
#pragma unroll
        for (int ni = 0; ni < 4; ni++) {
            bh[ni] = *(const short8*)&Bh[wn + ni * 16 + lm][q * 8];
            bl[ni] = *(const short8*)&Bl[wn + ni * 16 + lm][q * 8];
        }
#pragma unroll
        for (int mi = 0; mi < 4; mi++) {
            short8 ah = *(const short8*)&Xh[wm + mi * 16 + lm][q * 8];
            short8 al = *(const short8*)&Xl[wm + mi * 16 + lm][q * 8];
#pragma unroll
            for (int ni = 0; ni < 4; ni++) {
                acc[mi][ni] = __builtin_amdgcn_mfma_f32_16x16x32_bf16(ah, bh[ni], acc[mi][ni], 0, 0, 0);
                acc[mi][ni] = __builtin_amdgcn_mfma_f32_16x16x32_bf16(ah, bl[ni], acc[mi][ni], 0, 0, 0);
                acc[mi][ni] = __builtin_amdgcn_mfma_f32_16x16x32_bf16(al, bh[ni], acc[mi][ni], 0, 0, 0);
            }
        }
    }

    // epilogue: D[row=q*4+i][col=lm] per 16x16 tile
#pragma unroll
    for (int ni = 0; ni < 4; ni++) {
        const int col = wn + ni * 16 + lm;
        const float bv = BIAS ? bias[col] : 0.0f;
#pragma unroll
        for (int mi = 0; mi < 4; mi++) {
#pragma unroll
            for (int i = 0; i < 4; i++) {
                int row = m0 + wm + mi * 16 + q * 4 + i;
                if (row < M)
                    Cout[(size_t)(orow0 + row) * H + col] = acc[mi][ni][i] + bv;
            }
        }
    }
}

// ---------------------------------------------------------------- CSR gather + bias + ReLU
__launch_bounds__(256)
__global__ void k_aggregate(const float* __restrict__ y, const int* __restrict__ offs,
                            const int2* __restrict__ epack,
                            const float* __restrict__ dinv, const float* __restrict__ bias,
                            float* __restrict__ out) {
    const int node = blockIdx.x * 4 + (threadIdx.x >> 6);
    const int l    = threadIdx.x & 63;
    const int e0 = offs[node], e1 = offs[node + 1];
    const int deg = e1 - e0;

    const float2* y2 = (const float2*)y;
    float2 acc = make_float2(0.f, 0.f);

    for (int base = 0; base < deg; base += 64) {
        const int m = min(64, deg - base);
        int2 pk = (l < m) ? epack[e0 + base + l] : make_int2(0, 0);
#pragma unroll 4
        for (int j = 0; j < m; j++) {
            int   s = __builtin_amdgcn_readlane(pk.x, j);
            float w = __int_as_float(__builtin_amdgcn_readlane(pk.y, j));
            float2 v = y2[(size_t)s * 64 + l];
            acc.x = fmaf(w, v.x, acc.x);
            acc.y = fmaf(w, v.y, acc.y);
        }
    }

    const float  di = dinv[node];
    const float2 sv = y2[(size_t)node * 64 + l];
    const float2 bv = *(const float2*)&bias[2 * l];
    float rx = fmaf(sv.x, di * di, acc.x) + bv.x;
    float ry = fmaf(sv.y, di * di, acc.y) + bv.y;
    float2 o = make_float2(fmaxf(rx, 0.f), fmaxf(ry, 0.f));
    *((float2*)out + (size_t)node * 64 + l) = o;
}

// ---------------------------------------------------------------- output GEMM [NN,128]@[128,16]
__launch_bounds__(256, 2)
__global__ void k_out2(const float* __restrict__ X, const float* __restrict__ Wo,
                       const float* __restrict__ bo, float* __restrict__ out, int M) {
    __shared__ float As[128][128];
    const int tid  = threadIdx.x;
    const int m0   = blockIdx.x * 128;
    const int lrow = tid >> 1;
    const int koff = (tid & 1) * 64;
    const int grow = m0 + lrow;

    if (grow < M) {
        const float* p = &X[(size_t)grow * H + koff];
#pragma unroll
        for (int j = 0; j < 16; j++) {
            float4 v = *(const float4*)(p + 4 * j);
            As[koff + 4 * j + 0][lrow] = v.x;
            As[koff + 4 * j + 1][lrow] = v.y;
            As[koff + 4 * j + 2][lrow] = v.z;
            As[koff + 4 * j + 3][lrow] = v.w;
        }
    } else {
#pragma unroll
        for (int j = 0; j < 64; j++) As[koff + j][lrow] = 0.0f;
    }
    __syncthreads();

    const int o  = tid & 15;
    const int r0 = (tid >> 4) * 8;
    float acc[8];
    float bias = bo[o];
#pragma unroll
    for (int i = 0; i < 8; i++) acc[i] = bias;

#pragma unroll 4
    for (int kk = 0; kk < H; kk++) {
        float w  = Wo[kk * O + o];
        float4 a0 = *(const float4*)&As[kk][r0];
        float4 a1 = *(const float4*)&As[kk][r0 + 4];
        acc[0] = fmaf(a0.x, w, acc[0]); acc[1] = fmaf(a0.y, w, acc[1]);
        acc[2] = fmaf(a0.z, w, acc[2]); acc[3] = fmaf(a0.w, w, acc[3]);
        acc[4] = fmaf(a1.x, w, acc[4]); acc[5] = fmaf(a1.y, w, acc[5]);
        acc[6] = fmaf(a1.z, w, acc[6]); acc[7] = fmaf(a1.w, w, acc[7]);
    }
#pragma unroll
    for (int i = 0; i < 8; i++) {
        int r = m0 + r0 + i;
        if (r < M) out[(size_t)r * O + o] = acc[i];
    }
}

// ---------------------------------------------------------------- launch
extern "C" void kernel_launch(void* const* d_in, const int* in_sizes, int n_in,
                              void* d_out, int out_size, void* d_ws, size_t ws_size,
                              hipStream_t stream) {
    const float* user = (const float*)d_in[0];
    const float* prod = (const float*)d_in[1];
    const int*   eidx = (const int*)  d_in[2];
    const int*   edst = eidx + NE;
    const int*   esrc_in = eidx;
    const float* Wu = (const float*)d_in[3];
    const float* bu = (const float*)d_in[4];
    const float* Wp = (const float*)d_in[5];
    const float* bp = (const float*)d_in[6];
    const float* W1 = (const float*)d_in[7];
    const float* b1 = (const float*)d_in[8];
    const float* W2 = (const float*)d_in[9];
    const float* b2 = (const float*)d_in[10];
    const float* W3 = (const float*)d_in[11];
    const float* b3 = (const float*)d_in[12];
    const float* Wo = (const float*)d_in[13];
    const float* bo = (const float*)d_in[14];
    float* out = (float*)d_out;

    char* ws = (char*)d_ws;
    size_t p = 0;
    auto alloc = [&](size_t bytes) -> void* {
        void* r = ws + p;
        p += (bytes + 255) & ~(size_t)255;
        return r;
    };
    float* xA    = (float*)alloc((size_t)NN * H * 4);
    float* xB    = (float*)alloc((size_t)NN * H * 4);
    int*   cnt   = (int*)  alloc((size_t)NN * 4);
    int*   cursor= (int*)  alloc((size_t)NN * 4);
    int*   offs  = (int*)  alloc((size_t)(NN + 1) * 4);
    float* dinv  = (float*)alloc((size_t)NN * 4);
    int2*  epack = (int2*) alloc((size_t)NE * 8);
    int*   bsums = (int*)  alloc(128 * 4);
    short* whU = (short*)alloc(128 * 64 * 2);
    short* wlU = (short*)alloc(128 * 64 * 2);
    short* whP = (short*)alloc(128 * 128 * 2);
    short* wlP = (short*)alloc(128 * 128 * 2);
    short* wh1 = (short*)alloc(128 * 128 * 2);
    short* wl1 = (short*)alloc(128 * 128 * 2);
    short* wh2 = (short*)alloc(128 * 128 * 2);
    short* wl2 = (short*)alloc(128 * 128 * 2);
    short* wh3 = (short*)alloc(128 * 128 * 2);
    short* wl3 = (short*)alloc(128 * 128 * 2);

    const int NBLK = (NN + SCAN_CHUNK - 1) / SCAN_CHUNK;

    // weight prep (split + transpose, once per call)
    k_wprep<<<(128 *  64 + 255) / 256, 256, 0, stream>>>(Wu, whU, wlU,  64,  64);
    k_wprep<<<(128 * 128 + 255) / 256, 256, 0, stream>>>(Wp, whP, wlP, 100, 128);
    k_wprep<<<(128 * 128 + 255) / 256, 256, 0, stream>>>(W1, wh1, wl1, 128, 128);
    k_wprep<<<(128 * 128 + 255) / 256, 256, 0, stream>>>(W2, wh2, wl2, 128, 128);
    k_wprep<<<(128 * 128 + 255) / 256, 256, 0, stream>>>(W3, wh3, wl3, 128, 128);

    // graph structure (once per call)
    k_init <<<(NN + 255) / 256, 256, 0, stream>>>(cnt, cursor, NN);
    k_count<<<(NE + 255) / 256, 256, 0, stream>>>(edst, cnt, NE);
    k_dinv <<<(NN + 255) / 256, 256, 0, stream>>>(cnt, dinv, NN);
    k_scan1<<<NBLK, SCAN_TPB, 0, stream>>>(cnt, offs, bsums, NN);
    k_scan2<<<1, 128, 0, stream>>>(bsums, NBLK, offs + NN);
    k_scan3<<<(NN + 255) / 256, 256, 0, stream>>>(offs, bsums, NN);
    k_fill <<<(NE + 255) / 256, 256, 0, stream>>>(esrc_in, edst, offs, cursor, dinv,
                                                  epack, NE);

    // input feature transforms -> xA
    k_gemm_mx< 64,  64, true><<<(NU + 127) / 128, 256, 0, stream>>>(user, whU, wlU, bu, xA, NU, 0);
    k_gemm_mx<100, 128, true><<<(NP + 127) / 128, 256, 0, stream>>>(prod, whP, wlP, bp, xA, NP, NU);

    // layer 1
    k_gemm_mx<128, 128, false><<<(NN + 127) / 128, 256, 0, stream>>>(xA, wh1, wl1, nullptr, xB, NN, 0);
    k_aggregate<<<NN / 4, 256, 0, stream>>>(xB, offs, epack, dinv, b1, xA);
    // layer 2
    k_gemm_mx<128, 128, false><<<(NN + 127) / 128, 256, 0, stream>>>(xA, wh2, wl2, nullptr, xB, NN, 0);
    k_aggregate<<<NN / 4, 256, 0, stream>>>(xB, offs, epack, dinv, b2, xA);
    // layer 3
    k_gemm_mx<128, 128, false><<<(NN + 127) / 128, 256, 0, stream>>>(xA, wh3, wl3, nullptr, xB, NN, 0);
    k_aggregate<<<NN / 4, 256, 0, stream>>>(xB, offs, epack, dinv, b3, xA);

    // output head
    k_out2<<<(NN + 127) / 128, 256, 0, stream>>>(xA, Wo, bo, out, NN);
}

// Round 8
// 495.930 us; speedup vs baseline: 1.3525x; 1.0885x over previous
//
#include <hip/hip_runtime.h>
#include <hip/hip_fp16.h>

#define NU 50000
#define NP 50000
#define NN 100000
#define NE 600000
#define H  128
#define O  16

typedef __attribute__((ext_vector_type(8))) short short8;
typedef __attribute__((ext_vector_type(4))) float f32x4;

// split fp32 into bf16 hi + bf16 lo (RNE); x ≈ hi + lo to ~2^-17 rel
__device__ inline void split_bf16(float x, short& h, short& l) {
    unsigned u  = __float_as_uint(x);
    unsigned hb = (u + 0x7fffu + ((u >> 16) & 1u)) & 0xffff0000u;
    h = (short)(hb >> 16);
    float lo = x - __uint_as_float(hb);
    unsigned ul = __float_as_uint(lo);
    l = (short)((ul + 0x7fffu + ((ul >> 16) & 1u)) >> 16);
}

// ---------------------------------------------------------------- init / degree
__global__ void k_init(int* __restrict__ cnt, int* __restrict__ cursor, int n) {
    int i = blockIdx.x * blockDim.x + threadIdx.x;
    if (i < n) { cnt[i] = 0; cursor[i] = 0; }
}

__global__ void k_count(const int* __restrict__ dst, int* __restrict__ cnt, int E) {
    int e = blockIdx.x * blockDim.x + threadIdx.x;
    if (e < E) atomicAdd(&cnt[dst[e]], 1);
}

__global__ void k_dinv(const int* __restrict__ cnt, float* __restrict__ dinv, int n) {
    int i = blockIdx.x * blockDim.x + threadIdx.x;
    if (i < n) dinv[i] = rsqrtf((float)(cnt[i] + 1));
}

// ---------------------------------------------------------------- exclusive scan
#define SCAN_TPB 256
#define SCAN_VPT 4
#define SCAN_CHUNK (SCAN_TPB * SCAN_VPT)

__global__ void k_scan1(const int* __restrict__ in, int* __restrict__ out,
                        int* __restrict__ bsums, int n) {
    __shared__ int sh[SCAN_TPB];
    int t = threadIdx.x, b = blockIdx.x;
    int base = b * SCAN_CHUNK + t * SCAN_VPT;
    int v[SCAN_VPT]; int s = 0;
#pragma unroll
    for (int i = 0; i < SCAN_VPT; i++) {
        int idx = base + i;
        v[i] = (idx < n) ? in[idx] : 0;
        s += v[i];
    }
    sh[t] = s; __syncthreads();
    for (int off = 1; off < SCAN_TPB; off <<= 1) {
        int x = (t >= off) ? sh[t - off] : 0;
        __syncthreads();
        sh[t] += x;
        __syncthreads();
    }
    int run = (t > 0) ? sh[t - 1] : 0;
    if (t == SCAN_TPB - 1) bsums[b] = sh[t];
#pragma unroll
    for (int i = 0; i < SCAN_VPT; i++) {
        int idx = base + i;
        if (idx < n) out[idx] = run;
        run += v[i];
    }
}

__global__ void k_scan2(int* __restrict__ bsums, int nb, int* __restrict__ total) {
    __shared__ int sh[128];
    int t = threadIdx.x;
    int v = (t < nb) ? bsums[t] : 0;
    sh[t] = v; __syncthreads();
    for (int off = 1; off < 128; off <<= 1) {
        int x = (t >= off) ? sh[t - off] : 0;
        __syncthreads();
        sh[t] += x;
        __syncthreads();
    }
    if (t < nb) bsums[t] = sh[t] - v;
    if (t == 127) *total = sh[127];
}

__global__ void k_scan3(int* __restrict__ out, const int* __restrict__ bsums, int n) {
    int idx = blockIdx.x * blockDim.x + threadIdx.x;
    if (idx < n) out[idx] += bsums[idx / SCAN_CHUNK];
}

// ---------------------------------------------------------------- CSR fill
__global__ void k_fill(const int* __restrict__ src, const int* __restrict__ dst,
                       const int* __restrict__ offs, int* __restrict__ cursor,
                       const float* __restrict__ dinv,
                       int2* __restrict__ epack, int E) {
    int e = blockIdx.x * blockDim.x + threadIdx.x;
    if (e < E) {
        int s = src[e], d = dst[e];
        int p = offs[d] + atomicAdd(&cursor[d], 1);
        int2 r;
        r.x = s;
        r.y = __float_as_int(dinv[s] * dinv[d]);
        epack[p] = r;
    }
}

// ---------------------------------------------------------------- weight prep
// W[K][128] fp32 -> bf16 hi/lo, transposed [n][KPAD] (k-contig, zero-padded).
__global__ void k_wprep(const float* __restrict__ W, short* __restrict__ Wh,
                        short* __restrict__ Wl, int K, int KPAD) {
    int idx = blockIdx.x * blockDim.x + threadIdx.x;
    if (idx >= 128 * KPAD) return;
    int n = idx / KPAD, k = idx - n * KPAD;
    float x = (k < K) ? W[k * H + n] : 0.0f;
    short h, l; split_bf16(x, h, l);
    Wh[idx] = h; Wl[idx] = l;
}

// ---------------------------------------------------------------- MFMA GEMM (split-bf16)
// C[M,128](fp16) = A[M,K] @ W[K,128] (+bias); A is fp32 or fp16 (template).
// x*w ~= xh*wh + xh*wl + xl*wh. 256 thr = 4 waves (2x2), 128x128 tile, BK=32.
template <typename AT, int K, int KPAD, bool BIAS>
__launch_bounds__(256)
__global__ void k_gemm_mx(const AT* __restrict__ A, const short* __restrict__ Wh,
                          const short* __restrict__ Wl, const float* __restrict__ bias,
                          __half* __restrict__ Cout, int M, int orow0) {
    __shared__ __align__(16) short Xh[128][32], Xl[128][32];
    __shared__ __align__(16) short Bh[128][32], Bl[128][32];

    const int tid  = threadIdx.x;
    const int m0   = blockIdx.x * 128;
    const int wid  = tid >> 6, lane = tid & 63;
    const int wm   = (wid >> 1) * 64, wn = (wid & 1) * 64;
    const int lm   = lane & 15,  q  = lane >> 4;

    const int s_row  = tid >> 1;
    const int s_half = tid & 1;
    const int grow   = m0 + s_row;

    float xv[16];
    uint4 wvh[2], wvl[2];

    auto gload = [&](int k0) {
        const int kb = k0 + s_half * 16;
        if (grow < M && kb + 16 <= K) {
            if constexpr (sizeof(AT) == 4) {
                const float* p = (const float*)A + (size_t)grow * K + kb;
#pragma unroll
                for (int j = 0; j < 4; j++) {
                    float4 v = *(const float4*)(p + 4 * j);
                    xv[4*j] = v.x; xv[4*j+1] = v.y; xv[4*j+2] = v.z; xv[4*j+3] = v.w;
                }
            } else {
                const __half* p = (const __half*)A + (size_t)grow * K + kb;
                short8 v0 = *(const short8*)p;
                short8 v1 = *(const short8*)(p + 8);
#pragma unroll
                for (int j = 0; j < 8; j++) {
                    xv[j]     = __half2float(__ushort_as_half((unsigned short)v0[j]));
                    xv[j + 8] = __half2float(__ushort_as_half((unsigned short)v1[j]));
                }
            }
        } else {
#pragma unroll
            for (int j = 0; j < 16; j++) {
                int k = kb + j;
                float x = 0.0f;
                if (grow < M && k < K) {
                    if constexpr (sizeof(AT) == 4) x = ((const float*)A)[(size_t)grow * K + k];
                    else x = __half2float(((const __half*)A)[(size_t)grow * K + k]);
                }
                xv[j] = x;
            }
        }
        const short* ph = &Wh[s_row * KPAD + kb];
        const short* pl = &Wl[s_row * KPAD + kb];
        wvh[0] = *(const uint4*)ph; wvh[1] = *(const uint4*)(ph + 8);
        wvl[0] = *(const uint4*)pl; wvl[1] = *(const uint4*)(pl + 8);
    };

    auto sstore = [&]() {
        short8 h0, h1, l0, l1;
#pragma unroll
        for (int j = 0; j < 8; j++) {
            short hh, ll;
            split_bf16(xv[j], hh, ll);     h0[j] = hh; l0[j] = ll;
            split_bf16(xv[j + 8], hh, ll); h1[j] = hh; l1[j] = ll;
        }
        *(short8*)&Xh[s_row][s_half * 16]     = h0;
        *(short8*)&Xh[s_row][s_half * 16 + 8] = h1;
        *(short8*)&Xl[s_row][s_half * 16]     = l0;
        *(short8*)&Xl[s_row][s_half * 16 + 8] = l1;
        *(uint4*)&Bh[s_row][s_half * 16]      = wvh[0];
        *(uint4*)&Bh[s_row][s_half * 16 + 8]  = wvh[1];
        *(uint4*)&Bl[s_row][s_half * 16]      = wvl[0];
        *(uint4*)&Bl[s_row][s_half * 16 + 8]  = wvl[1];
    };

    f32x4 acc[4][4];
#pragma unroll
    for (int i = 0; i < 4; i++)
#pragma unroll
        for (int j = 0; j < 4; j++) acc[i][j] = (f32x4)0.0f;

    const int NCH = KPAD / 32;
    gload(0);

    for (int ch = 0; ch < NCH; ch++) {
        __syncthreads();
        sstore();
        __syncthreads();
        if (ch + 1 < NCH) gload((ch + 1) * 32);

        short8 bh[4], bl[4];
#pragma unroll
        for (int ni = 0; ni < 4; ni++) {
            bh[ni] = *(const short8*)&Bh[wn + ni * 16 + lm][q * 8];
            bl[ni] = *(const short8*)&Bl[wn + ni * 16 + lm][q * 8];
        }
#pragma unroll
        for (int mi = 0; mi < 4; mi++) {
            short8 ah = *(const short8*)&Xh[wm + mi * 16 + lm][q * 8];
            short8 al = *(const short8*)&Xl[wm + mi * 16 + lm][q * 8];
#pragma unroll
            for (int ni = 0; ni < 4; ni++) {
                acc[mi][ni] = __builtin_amdgcn_mfma_f32_16x16x32_bf16(ah, bh[ni], acc[mi][ni], 0, 0, 0);
                acc[mi][ni] = __builtin_amdgcn_mfma_f32_16x16x32_bf16(ah, bl[ni], acc[mi][ni], 0, 0, 0);
                acc[mi][ni] = __builtin_amdgcn_mfma_f32_16x16x32_bf16(al, bh[ni], acc[mi][ni], 0, 0, 0);
            }
        }
    }

    // epilogue: D[row=q*4+i][col=lm] per 16x16 tile, fp16 store
#pragma unroll
    for (int ni = 0; ni < 4; ni++) {
        const int col = wn + ni * 16 + lm;
        const float bv = BIAS ? bias[col] : 0.0f;
#pragma unroll
        for (int mi = 0; mi < 4; mi++) {
#pragma unroll
            for (int i = 0; i < 4; i++) {
                int row = m0 + wm + mi * 16 + q * 4 + i;
                if (row < M)
                    Cout[(size_t)(orow0 + row) * H + col] = __float2half_rn(acc[mi][ni][i] + bv);
            }
        }
    }
}

// ---------------------------------------------------------------- CSR gather + bias + ReLU
// One WAVE per node: 64 lanes x half2 = 256B row; fp32 accumulate; fp16 out.
__launch_bounds__(256)
__global__ void k_aggregate(const __half* __restrict__ y, const int* __restrict__ offs,
                            const int2* __restrict__ epack,
                            const float* __restrict__ dinv, const float* __restrict__ bias,
                            __half* __restrict__ out) {
    const int node = blockIdx.x * 4 + (threadIdx.x >> 6);
    const int l    = threadIdx.x & 63;
    const int e0 = offs[node], e1 = offs[node + 1];
    const int deg = e1 - e0;

    const __half2* y2 = (const __half2*)y;    // row stride = 64 half2
    float2 acc = make_float2(0.f, 0.f);

    for (int base = 0; base < deg; base += 64) {
        const int m = min(64, deg - base);
        int2 pk = (l < m) ? epack[e0 + base + l] : make_int2(0, 0);
#pragma unroll 4
        for (int j = 0; j < m; j++) {
            int   s = __builtin_amdgcn_readlane(pk.x, j);
            float w = __int_as_float(__builtin_amdgcn_readlane(pk.y, j));
            float2 v = __half22float2(y2[(size_t)s * 64 + l]);   // 256B row
            acc.x = fmaf(w, v.x, acc.x);
            acc.y = fmaf(w, v.y, acc.y);
        }
    }

    const float  di = dinv[node];
    const float2 sv = __half22float2(y2[(size_t)node * 64 + l]);
    const float2 bv = *(const float2*)&bias[2 * l];
    float rx = fmaf(sv.x, di * di, acc.x) + bv.x;
    float ry = fmaf(sv.y, di * di, acc.y) + bv.y;
    ((__half2*)out)[(size_t)node * 64 + l] =
        __floats2half2_rn(fmaxf(rx, 0.f), fmaxf(ry, 0.f));
}

// ---------------------------------------------------------------- output GEMM [NN,128]@[128,16]
// Full X row-tile transposed in LDS (fp32 after convert), ONE barrier.
__launch_bounds__(256, 2)
__global__ void k_out2(const __half* __restrict__ X, const float* __restrict__ Wo,
                       const float* __restrict__ bo, float* __restrict__ out, int M) {
    __shared__ float As[128][128];
    const int tid  = threadIdx.x;
    const int m0   = blockIdx.x * 128;
    const int lrow = tid >> 1;
    const int koff = (tid & 1) * 64;
    const int grow = m0 + lrow;

    if (grow < M) {
        const __half* p = &X[(size_t)grow * H + koff];
#pragma unroll
        for (int j = 0; j < 8; j++) {
            short8 v = *(const short8*)(p + 8 * j);
#pragma unroll
            for (int i = 0; i < 8; i++)
                As[koff + 8 * j + i][lrow] = __half2float(__ushort_as_half((unsigned short)v[i]));
        }
    } else {
#pragma unroll
        for (int j = 0; j < 64; j++) As[koff + j][lrow] = 0.0f;
    }
    __syncthreads();

    const int o  = tid & 15;
    const int r0 = (tid >> 4) * 8;
    float acc[8];
    float bias = bo[o];
#pragma unroll
    for (int i = 0; i < 8; i++) acc[i] = bias;

#pragma unroll 4
    for (int kk = 0; kk < H; kk++) {
        float w  = Wo[kk * O + o];
        float4 a0 = *(const float4*)&As[kk][r0];
        float4 a1 = *(const float4*)&As[kk][r0 + 4];
        acc[0] = fmaf(a0.x, w, acc[0]); acc[1] = fmaf(a0.y, w, acc[1]);
        acc[2] = fmaf(a0.z, w, acc[2]); acc[3] = fmaf(a0.w, w, acc[3]);
        acc[4] = fmaf(a1.x, w, acc[4]); acc[5] = fmaf(a1.y, w, acc[5]);
        acc[6] = fmaf(a1.z, w, acc[6]); acc[7] = fmaf(a1.w, w, acc[7]);
    }
#pragma unroll
    for (int i = 0; i < 8; i++) {
        int r = m0 + r0 + i;
        if (r < M) out[(size_t)r * O + o] = acc[i];
    }
}

// ---------------------------------------------------------------- launch
extern "C" void kernel_launch(void* const* d_in, const int* in_sizes, int n_in,
                              void* d_out, int out_size, void* d_ws, size_t ws_size,
                              hipStream_t stream) {
    const float* user = (const float*)d_in[0];
    const float* prod = (const float*)d_in[1];
    const int*   eidx = (const int*)  d_in[2];
    const int*   edst = eidx + NE;
    const int*   esrc_in = eidx;
    const float* Wu = (const float*)d_in[3];
    const float* bu = (const float*)d_in[4];
    const float* Wp = (const float*)d_in[5];
    const float* bp = (const float*)d_in[6];
    const float* W1 = (const float*)d_in[7];
    const float* b1 = (const float*)d_in[8];
    const float* W2 = (const float*)d_in[9];
    const float* b2 = (const float*)d_in[10];
    const float* W3 = (const float*)d_in[11];
    const float* b3 = (const float*)d_in[12];
    const float* Wo = (const float*)d_in[13];
    const float* bo = (const float*)d_in[14];
    float* out = (float*)d_out;

    char* ws = (char*)d_ws;
    size_t p = 0;
    auto alloc = [&](size_t bytes) -> void* {
        void* r = ws + p;
        p += (bytes + 255) & ~(size_t)255;
        return r;
    };
    __half* xA   = (__half*)alloc((size_t)NN * H * 2);
    __half* xB   = (__half*)alloc((size_t)NN * H * 2);
    int*   cnt   = (int*)  alloc((size_t)NN * 4);
    int*   cursor= (int*)  alloc((size_t)NN * 4);
    int*   offs  = (int*)  alloc((size_t)(NN + 1) * 4);
    float* dinv  = (float*)alloc((size_t)NN * 4);
    int2*  epack = (int2*) alloc((size_t)NE * 8);
    int*   bsums = (int*)  alloc(128 * 4);
    short* whU = (short*)alloc(128 * 64 * 2);
    short* wlU = (short*)alloc(128 * 64 * 2);
    short* whP = (short*)alloc(128 * 128 * 2);
    short* wlP = (short*)alloc(128 * 128 * 2);
    short* wh1 = (short*)alloc(128 * 128 * 2);
    short* wl1 = (short*)alloc(128 * 128 * 2);
    short* wh2 = (short*)alloc(128 * 128 * 2);
    short* wl2 = (short*)alloc(128 * 128 * 2);
    short* wh3 = (short*)alloc(128 * 128 * 2);
    short* wl3 = (short*)alloc(128 * 128 * 2);

    const int NBLK = (NN + SCAN_CHUNK - 1) / SCAN_CHUNK;

    // weight prep (split + transpose, once per call)
    k_wprep<<<(128 *  64 + 255) / 256, 256, 0, stream>>>(Wu, whU, wlU,  64,  64);
    k_wprep<<<(128 * 128 + 255) / 256, 256, 0, stream>>>(Wp, whP, wlP, 100, 128);
    k_wprep<<<(128 * 128 + 255) / 256, 256, 0, stream>>>(W1, wh1, wl1, 128, 128);
    k_wprep<<<(128 * 128 + 255) / 256, 256, 0, stream>>>(W2, wh2, wl2, 128, 128);
    k_wprep<<<(128 * 128 + 255) / 256, 256, 0, stream>>>(W3, wh3, wl3, 128, 128);

    // graph structure (once per call)
    k_init <<<(NN + 255) / 256, 256, 0, stream>>>(cnt, cursor, NN);
    k_count<<<(NE + 255) / 256, 256, 0, stream>>>(edst, cnt, NE);
    k_dinv <<<(NN + 255) / 256, 256, 0, stream>>>(cnt, dinv, NN);
    k_scan1<<<NBLK, SCAN_TPB, 0, stream>>>(cnt, offs, bsums, NN);
    k_scan2<<<1, 128, 0, stream>>>(bsums, NBLK, offs + NN);
    k_scan3<<<(NN + 255) / 256, 256, 0, stream>>>(offs, bsums, NN);
    k_fill <<<(NE + 255) / 256, 256, 0, stream>>>(esrc_in, edst, offs, cursor, dinv,
                                                  epack, NE);

    // input feature transforms -> xA (fp16)
    k_gemm_mx<float,  64,  64, true><<<(NU + 127) / 128, 256, 0, stream>>>(user, whU, wlU, bu, xA, NU, 0);
    k_gemm_mx<float, 100, 128, true><<<(NP + 127) / 128, 256, 0, stream>>>(prod, whP, wlP, bp, xA, NP, NU);

    // layer 1
    k_gemm_mx<__half, 128, 128, false><<<(NN + 127) / 128, 256, 0, stream>>>(xA, wh1, wl1, nullptr, xB, NN, 0);
    k_aggregate<<<NN / 4, 256, 0, stream>>>(xB, offs, epack, dinv, b1, xA);
    // layer 2
    k_gemm_mx<__half, 128, 128, false><<<(NN + 127) / 128, 256, 0, stream>>>(xA, wh2, wl2, nullptr, xB, NN, 0);
    k_aggregate<<<NN / 4, 256, 0, stream>>>(xB, offs, epack, dinv, b2, xA);
    // layer 3
    k_gemm_mx<__half, 128, 128, false><<<(NN + 127) / 128, 256, 0, stream>>>(xA, wh3, wl3, nullptr, xB, NN, 0);
    k_aggregate<<<NN / 4, 256, 0, stream>>>(xB, offs, epack, dinv, b3, xA);

    // output head
    k_out2<<<(NN + 127) / 128, 256, 0, stream>>>(xA, Wo, bo, out, NN);
}

// Round 9
// 466.629 us; speedup vs baseline: 1.4375x; 1.0628x over previous
//
#include <hip/hip_runtime.h>
#include <hip/hip_fp16.h>

#define NU 50000
#define NP 50000
#define NN 100000
#define NE 600000
#define H  128
#define O  16

typedef __attribute__((ext_vector_type(8))) _Float16 half8;
typedef __attribute__((ext_vector_type(8))) short short8;
typedef __attribute__((ext_vector_type(4))) float f32x4;

// ---------------------------------------------------------------- init / degree
__global__ void k_init(int* __restrict__ cnt, int* __restrict__ cursor, int n) {
    int i = blockIdx.x * blockDim.x + threadIdx.x;
    if (i < n) { cnt[i] = 0; cursor[i] = 0; }
}

__global__ void k_count(const int* __restrict__ dst, int* __restrict__ cnt, int E) {
    int e = blockIdx.x * blockDim.x + threadIdx.x;
    if (e < E) atomicAdd(&cnt[dst[e]], 1);
}

__global__ void k_dinv(const int* __restrict__ cnt, float* __restrict__ dinv, int n) {
    int i = blockIdx.x * blockDim.x + threadIdx.x;
    if (i < n) dinv[i] = rsqrtf((float)(cnt[i] + 1));
}

// ---------------------------------------------------------------- exclusive scan
#define SCAN_TPB 256
#define SCAN_VPT 4
#define SCAN_CHUNK (SCAN_TPB * SCAN_VPT)

__global__ void k_scan1(const int* __restrict__ in, int* __restrict__ out,
                        int* __restrict__ bsums, int n) {
    __shared__ int sh[SCAN_TPB];
    int t = threadIdx.x, b = blockIdx.x;
    int base = b * SCAN_CHUNK + t * SCAN_VPT;
    int v[SCAN_VPT]; int s = 0;
#pragma unroll
    for (int i = 0; i < SCAN_VPT; i++) {
        int idx = base + i;
        v[i] = (idx < n) ? in[idx] : 0;
        s += v[i];
    }
    sh[t] = s; __syncthreads();
    for (int off = 1; off < SCAN_TPB; off <<= 1) {
        int x = (t >= off) ? sh[t - off] : 0;
        __syncthreads();
        sh[t] += x;
        __syncthreads();
    }
    int run = (t > 0) ? sh[t - 1] : 0;
    if (t == SCAN_TPB - 1) bsums[b] = sh[t];
#pragma unroll
    for (int i = 0; i < SCAN_VPT; i++) {
        int idx = base + i;
        if (idx < n) out[idx] = run;
        run += v[i];
    }
}

__global__ void k_scan2(int* __restrict__ bsums, int nb, int* __restrict__ total) {
    __shared__ int sh[128];
    int t = threadIdx.x;
    int v = (t < nb) ? bsums[t] : 0;
    sh[t] = v; __syncthreads();
    for (int off = 1; off < 128; off <<= 1) {
        int x = (t >= off) ? sh[t - off] : 0;
        __syncthreads();
        sh[t] += x;
        __syncthreads();
    }
    if (t < nb) bsums[t] = sh[t] - v;
    if (t == 127) *total = sh[127];
}

__global__ void k_scan3(int* __restrict__ out, const int* __restrict__ bsums, int n) {
    int idx = blockIdx.x * blockDim.x + threadIdx.x;
    if (idx < n) out[idx] += bsums[idx / SCAN_CHUNK];
}

// ---------------------------------------------------------------- CSR fill
__global__ void k_fill(const int* __restrict__ src, const int* __restrict__ dst,
                       const int* __restrict__ offs, int* __restrict__ cursor,
                       const float* __restrict__ dinv,
                       int2* __restrict__ epack, int E) {
    int e = blockIdx.x * blockDim.x + threadIdx.x;
    if (e < E) {
        int s = src[e], d = dst[e];
        int p = offs[d] + atomicAdd(&cursor[d], 1);
        int2 r;
        r.x = s;
        r.y = __float_as_int(dinv[s] * dinv[d]);
        epack[p] = r;
    }
}

// ---------------------------------------------------------------- weight prep
// W[K][128] fp32 -> f16 hi + f16 lo, SCALED x16 (keeps lo out of the f16
// subnormal-flush zone), transposed [n][KPAD] k-contig, zero-padded.
__global__ void k_wprep16(const float* __restrict__ W, __half* __restrict__ Wh,
                          __half* __restrict__ Wl, int K, int KPAD) {
    int idx = blockIdx.x * blockDim.x + threadIdx.x;
    if (idx >= 128 * KPAD) return;
    int n = idx / KPAD, k = idx - n * KPAD;
    float x = (k < K) ? W[k * H + n] * 16.0f : 0.0f;
    __half h = __float2half_rn(x);
    __half l = __float2half_rn(x - __half2float(h));
    Wh[idx] = h; Wl[idx] = l;
}

// ---------------------------------------------------------------- MFMA GEMM (2-term f16)
// C[M,128](fp16) = A[M,K] @ W[K,128] (+bias). A fp32 or fp16 (template).
// x*w = x*wh + x*wl exactly to ~2^-22 (W pre-scaled x16, unscaled in epilogue).
// 256 thr = 4 waves (2x2), 128x128 tile, BK=32, LDS rows padded to 40 shorts
// (80B stride -> bank-start (20r+4q)%32 uniform over 32 banks: conflict-free).
template <typename AT, int K, int KPAD, bool BIAS>
__launch_bounds__(256)
__global__ void k_gemm16(const AT* __restrict__ A, const __half* __restrict__ Wh,
                         const __half* __restrict__ Wl, const float* __restrict__ bias,
                         __half* __restrict__ Cout, int M, int orow0) {
    __shared__ __align__(16) short Xs [128][40];
    __shared__ __align__(16) short Bhs[128][40];
    __shared__ __align__(16) short Bls[128][40];

    const int tid  = threadIdx.x;
    const int m0   = blockIdx.x * 128;
    const int wid  = tid >> 6, lane = tid & 63;
    const int wm   = (wid >> 1) * 64, wn = (wid & 1) * 64;
    const int lm   = lane & 15,  q  = lane >> 4;

    const int s_row  = tid >> 1;          // 0..127
    const int s_half = tid & 1;           // k-offset 0 / 16
    const int grow   = m0 + s_row;

    short8 xs0, xs1;                      // 16 halves of A (as raw shorts)
    uint4  wvh[2], wvl[2];

    auto gload = [&](int k0) {
        const int kb = k0 + s_half * 16;
        if constexpr (sizeof(AT) == 2) {
            if (grow < M) {               // KPAD==K==128 for fp16 path
                const __half* p = (const __half*)A + (size_t)grow * K + kb;
                xs0 = *(const short8*)p;
                xs1 = *(const short8*)(p + 8);
            } else { xs0 = (short8)0; xs1 = (short8)0; }
        } else {
            float xv[16];
            if (grow < M && kb + 16 <= K) {
                const float* p = (const float*)A + (size_t)grow * K + kb;
#pragma unroll
                for (int j = 0; j < 4; j++) {
                    float4 v = *(const float4*)(p + 4 * j);
                    xv[4*j] = v.x; xv[4*j+1] = v.y; xv[4*j+2] = v.z; xv[4*j+3] = v.w;
                }
            } else {
#pragma unroll
                for (int j = 0; j < 16; j++) {
                    int k = kb + j;
                    xv[j] = (grow < M && k < K) ? ((const float*)A)[(size_t)grow * K + k] : 0.0f;
                }
            }
#pragma unroll
            for (int j = 0; j < 8; j++) {
                xs0[j] = (short)__half_as_ushort(__float2half_rn(xv[j]));
                xs1[j] = (short)__half_as_ushort(__float2half_rn(xv[j + 8]));
            }
        }
        const __half* ph = &Wh[s_row * KPAD + kb];
        const __half* pl = &Wl[s_row * KPAD + kb];
        wvh[0] = *(const uint4*)ph; wvh[1] = *(const uint4*)(ph + 8);
        wvl[0] = *(const uint4*)pl; wvl[1] = *(const uint4*)(pl + 8);
    };

    auto sstore = [&]() {
        *(short8*)&Xs [s_row][s_half * 16]     = xs0;
        *(short8*)&Xs [s_row][s_half * 16 + 8] = xs1;
        *(uint4*)&Bhs[s_row][s_half * 16]      = wvh[0];
        *(uint4*)&Bhs[s_row][s_half * 16 + 8]  = wvh[1];
        *(uint4*)&Bls[s_row][s_half * 16]      = wvl[0];
        *(uint4*)&Bls[s_row][s_half * 16 + 8]  = wvl[1];
    };

    f32x4 acc[4][4];
#pragma unroll
    for (int i = 0; i < 4; i++)
#pragma unroll
        for (int j = 0; j < 4; j++) acc[i][j] = (f32x4)0.0f;

    const int NCH = KPAD / 32;
    gload(0);

    for (int ch = 0; ch < NCH; ch++) {
        __syncthreads();
        sstore();
        __syncthreads();
        if (ch + 1 < NCH) gload((ch + 1) * 32);

        half8 bh[4], bl[4];
#pragma unroll
        for (int ni = 0; ni < 4; ni++) {
            bh[ni] = *(const half8*)&Bhs[wn + ni * 16 + lm][q * 8];
            bl[ni] = *(const half8*)&Bls[wn + ni * 16 + lm][q * 8];
        }
#pragma unroll
        for (int mi = 0; mi < 4; mi++) {
            half8 a = *(const half8*)&Xs[wm + mi * 16 + lm][q * 8];
#pragma unroll
            for (int ni = 0; ni < 4; ni++) {
                acc[mi][ni] = __builtin_amdgcn_mfma_f32_16x16x32_f16(a, bh[ni], acc[mi][ni], 0, 0, 0);
                acc[mi][ni] = __builtin_amdgcn_mfma_f32_16x16x32_f16(a, bl[ni], acc[mi][ni], 0, 0, 0);
            }
        }
    }

    // epilogue: D[row=q*4+i][col=lm]; unscale x1/16, +bias, fp16 store
#pragma unroll
    for (int ni = 0; ni < 4; ni++) {
        const int col = wn + ni * 16 + lm;
        const float bv = BIAS ? bias[col] : 0.0f;
#pragma unroll
        for (int mi = 0; mi < 4; mi++) {
#pragma unroll
            for (int i = 0; i < 4; i++) {
                int row = m0 + wm + mi * 16 + q * 4 + i;
                if (row < M)
                    Cout[(size_t)(orow0 + row) * H + col] =
                        __float2half_rn(fmaf(acc[mi][ni][i], 0.0625f, bv));
            }
        }
    }
}

// ---------------------------------------------------------------- CSR gather + bias + ReLU
// One WAVE per node, TWO edges in flight: 32 lanes x 8B (4 halves) per row.
// Edge records batch-loaded (one int2/lane), broadcast via shfl; parity halves
// combined with xor-shuffle. fp32 accumulate, fp16 out.
__launch_bounds__(256)
__global__ void k_aggregate(const __half* __restrict__ y, const int* __restrict__ offs,
                            const int2* __restrict__ epack,
                            const float* __restrict__ dinv, const float* __restrict__ bias,
                            __half* __restrict__ out) {
    const int node = blockIdx.x * 4 + (threadIdx.x >> 6);
    const int l    = threadIdx.x & 63;
    const int g    = l >> 5;              // edge parity
    const int s    = l & 31;              // 8B segment in row (32 x 8B = 256B)
    const int e0 = offs[node], e1 = offs[node + 1];
    const int deg = e1 - e0;

    const uint2* yv = (const uint2*)y;    // row stride = 32 uint2
    float4 acc = make_float4(0.f, 0.f, 0.f, 0.f);

    for (int base = 0; base < deg; base += 64) {
        const int m = min(64, deg - base);
        int2 pk = (l < m) ? epack[e0 + base + l] : make_int2(0, 0);
        const int pairs = (m + 1) >> 1;
#pragma unroll 2
        for (int j = 0; j < pairs; j++) {
            int idx = 2 * j + g;
            int   sN = __shfl(pk.x, idx, 64);
            float w  = __int_as_float(__shfl(pk.y, idx, 64));
            if (idx < m) {
                uint2 v = yv[(size_t)sN * 32 + s];
                float2 f0 = __half22float2(*(const __half2*)&v.x);
                float2 f1 = __half22float2(*(const __half2*)&v.y);
                acc.x = fmaf(w, f0.x, acc.x);
                acc.y = fmaf(w, f0.y, acc.y);
                acc.z = fmaf(w, f1.x, acc.z);
                acc.w = fmaf(w, f1.y, acc.w);
            }
        }
    }

    // combine the two parity halves (lane l <-> l^32)
    acc.x += __shfl_xor(acc.x, 32, 64);
    acc.y += __shfl_xor(acc.y, 32, 64);
    acc.z += __shfl_xor(acc.z, 32, 64);
    acc.w += __shfl_xor(acc.w, 32, 64);

    const float  di  = dinv[node];
    const float  di2 = di * di;
    uint2 sv = yv[(size_t)node * 32 + s];
    float2 s0 = __half22float2(*(const __half2*)&sv.x);
    float2 s1 = __half22float2(*(const __half2*)&sv.y);
    const float4 bv = *(const float4*)&bias[4 * s];
    float r0 = fmaf(s0.x, di2, acc.x) + bv.x;
    float r1 = fmaf(s0.y, di2, acc.y) + bv.y;
    float r2 = fmaf(s1.x, di2, acc.z) + bv.z;
    float r3 = fmaf(s1.y, di2, acc.w) + bv.w;
    if (g == 0) {
        __half2 o0 = __floats2half2_rn(fmaxf(r0, 0.f), fmaxf(r1, 0.f));
        __half2 o1 = __floats2half2_rn(fmaxf(r2, 0.f), fmaxf(r3, 0.f));
        uint2 ov;
        ov.x = *(const unsigned*)&o0;
        ov.y = *(const unsigned*)&o1;
        ((uint2*)out)[(size_t)node * 32 + s] = ov;
    }
}

// ---------------------------------------------------------------- output GEMM [NN,128]@[128,16]
__launch_bounds__(256, 2)
__global__ void k_out2(const __half* __restrict__ X, const float* __restrict__ Wo,
                       const float* __restrict__ bo, float* __restrict__ out, int M) {
    __shared__ float As[128][128];
    const int tid  = threadIdx.x;
    const int m0   = blockIdx.x * 128;
    const int lrow = tid >> 1;
    const int koff = (tid & 1) * 64;
    const int grow = m0 + lrow;

    if (grow < M) {
        const __half* p = &X[(size_t)grow * H + koff];
#pragma unroll
        for (int j = 0; j < 8; j++) {
            short8 v = *(const short8*)(p + 8 * j);
#pragma unroll
            for (int i = 0; i < 8; i++)
                As[koff + 8 * j + i][lrow] = __half2float(__ushort_as_half((unsigned short)v[i]));
        }
    } else {
#pragma unroll
        for (int j = 0; j < 64; j++) As[koff + j][lrow] = 0.0f;
    }
    __syncthreads();

    const int o  = tid & 15;
    const int r0 = (tid >> 4) * 8;
    float acc[8];
    float bias = bo[o];
#pragma unroll
    for (int i = 0; i < 8; i++) acc[i] = bias;

#pragma unroll 4
    for (int kk = 0; kk < H; kk++) {
        float w  = Wo[kk * O + o];
        float4 a0 = *(const float4*)&As[kk][r0];
        float4 a1 = *(const float4*)&As[kk][r0 + 4];
        acc[0] = fmaf(a0.x, w, acc[0]); acc[1] = fmaf(a0.y, w, acc[1]);
        acc[2] = fmaf(a0.z, w, acc[2]); acc[3] = fmaf(a0.w, w, acc[3]);
        acc[4] = fmaf(a1.x, w, acc[4]); acc[5] = fmaf(a1.y, w, acc[5]);
        acc[6] = fmaf(a1.z, w, acc[6]); acc[7] = fmaf(a1.w, w, acc[7]);
    }
#pragma unroll
    for (int i = 0; i < 8; i++) {
        int r = m0 + r0 + i;
        if (r < M) out[(size_t)r * O + o] = acc[i];
    }
}

// ---------------------------------------------------------------- launch
extern "C" void kernel_launch(void* const* d_in, const int* in_sizes, int n_in,
                              void* d_out, int out_size, void* d_ws, size_t ws_size,
                              hipStream_t stream) {
    const float* user = (const float*)d_in[0];
    const float* prod = (const float*)d_in[1];
    const int*   eidx = (const int*)  d_in[2];
    const int*   edst = eidx + NE;
    const int*   esrc_in = eidx;
    const float* Wu = (const float*)d_in[3];
    const float* bu = (const float*)d_in[4];
    const float* Wp = (const float*)d_in[5];
    const float* bp = (const float*)d_in[6];
    const float* W1 = (const float*)d_in[7];
    const float* b1 = (const float*)d_in[8];
    const float* W2 = (const float*)d_in[9];
    const float* b2 = (const float*)d_in[10];
    const float* W3 = (const float*)d_in[11];
    const float* b3 = (const float*)d_in[12];
    const float* Wo = (const float*)d_in[13];
    const float* bo = (const float*)d_in[14];
    float* out = (float*)d_out;

    char* ws = (char*)d_ws;
    size_t p = 0;
    auto alloc = [&](size_t bytes) -> void* {
        void* r = ws + p;
        p += (bytes + 255) & ~(size_t)255;
        return r;
    };
    __half* xA   = (__half*)alloc((size_t)NN * H * 2);
    __half* xB   = (__half*)alloc((size_t)NN * H * 2);
    int*   cnt   = (int*)  alloc((size_t)NN * 4);
    int*   cursor= (int*)  alloc((size_t)NN * 4);
    int*   offs  = (int*)  alloc((size_t)(NN + 1) * 4);
    float* dinv  = (float*)alloc((size_t)NN * 4);
    int2*  epack = (int2*) alloc((size_t)NE * 8);
    int*   bsums = (int*)  alloc(128 * 4);
    __half* whU = (__half*)alloc(128 * 64 * 2);
    __half* wlU = (__half*)alloc(128 * 64 * 2);
    __half* whP = (__half*)alloc(128 * 128 * 2);
    __half* wlP = (__half*)alloc(128 * 128 * 2);
    __half* wh1 = (__half*)alloc(128 * 128 * 2);
    __half* wl1 = (__half*)alloc(128 * 128 * 2);
    __half* wh2 = (__half*)alloc(128 * 128 * 2);
    __half* wl2 = (__half*)alloc(128 * 128 * 2);
    __half* wh3 = (__half*)alloc(128 * 128 * 2);
    __half* wl3 = (__half*)alloc(128 * 128 * 2);

    const int NBLK = (NN + SCAN_CHUNK - 1) / SCAN_CHUNK;

    // weight prep (split + transpose + x16 scale, once per call)
    k_wprep16<<<(128 *  64 + 255) / 256, 256, 0, stream>>>(Wu, whU, wlU,  64,  64);
    k_wprep16<<<(128 * 128 + 255) / 256, 256, 0, stream>>>(Wp, whP, wlP, 100, 128);
    k_wprep16<<<(128 * 128 + 255) / 256, 256, 0, stream>>>(W1, wh1, wl1, 128, 128);
    k_wprep16<<<(128 * 128 + 255) / 256, 256, 0, stream>>>(W2, wh2, wl2, 128, 128);
    k_wprep16<<<(128 * 128 + 255) / 256, 256, 0, stream>>>(W3, wh3, wl3, 128, 128);

    // graph structure (once per call)
    k_init <<<(NN + 255) / 256, 256, 0, stream>>>(cnt, cursor, NN);
    k_count<<<(NE + 255) / 256, 256, 0, stream>>>(edst, cnt, NE);
    k_dinv <<<(NN + 255) / 256, 256, 0, stream>>>(cnt, dinv, NN);
    k_scan1<<<NBLK, SCAN_TPB, 0, stream>>>(cnt, offs, bsums, NN);
    k_scan2<<<1, 128, 0, stream>>>(bsums, NBLK, offs + NN);
    k_scan3<<<(NN + 255) / 256, 256, 0, stream>>>(offs, bsums, NN);
    k_fill <<<(NE + 255) / 256, 256, 0, stream>>>(esrc_in, edst, offs, cursor, dinv,
                                                  epack, NE);

    // input feature transforms -> xA (fp16)
    k_gemm16<float,  64,  64, true><<<(NU + 127) / 128, 256, 0, stream>>>(user, whU, wlU, bu, xA, NU, 0);
    k_gemm16<float, 100, 128, true><<<(NP + 127) / 128, 256, 0, stream>>>(prod, whP, wlP, bp, xA, NP, NU);

    // layer 1
    k_gemm16<__half, 128, 128, false><<<(NN + 127) / 128, 256, 0, stream>>>(xA, wh1, wl1, nullptr, xB, NN, 0);
    k_aggregate<<<NN / 4, 256, 0, stream>>>(xB, offs, epack, dinv, b1, xA);
    // layer 2
    k_gemm16<__half, 128, 128, false><<<(NN + 127) / 128, 256, 0, stream>>>(xA, wh2, wl2, nullptr, xB, NN, 0);
    k_aggregate<<<NN / 4, 256, 0, stream>>>(xB, offs, epack, dinv, b2, xA);
    // layer 3
    k_gemm16<__half, 128, 128, false><<<(NN + 127) / 128, 256, 0, stream>>>(xA, wh3, wl3, nullptr, xB, NN, 0);
    k_aggregate<<<NN / 4, 256, 0, stream>>>(xB, offs, epack, dinv, b3, xA);

    // output head
    k_out2<<<(NN + 127) / 128, 256, 0, stream>>>(xA, Wo, bo, out, NN);
}

// Round 10
// 428.212 us; speedup vs baseline: 1.5664x; 1.0897x over previous
//
#include <hip/hip_runtime.h>
#include <hip/hip_fp16.h>

#define NU 50000
#define NP 50000
#define NN 100000
#define NE 600000
#define H  128
#define O  16

typedef __attribute__((ext_vector_type(8))) _Float16 half8;
typedef __attribute__((ext_vector_type(4))) float f32x4;

// ---------------------------------------------------------------- init / degree
__global__ void k_init(int* __restrict__ cnt, int* __restrict__ cursor, int n) {
    int i = blockIdx.x * blockDim.x + threadIdx.x;
    if (i < n) { cnt[i] = 0; cursor[i] = 0; }
}

__global__ void k_count(const int* __restrict__ dst, int* __restrict__ cnt, int E) {
    int e = blockIdx.x * blockDim.x + threadIdx.x;
    if (e < E) atomicAdd(&cnt[dst[e]], 1);
}

__global__ void k_dinv(const int* __restrict__ cnt, float* __restrict__ dinv, int n) {
    int i = blockIdx.x * blockDim.x + threadIdx.x;
    if (i < n) dinv[i] = rsqrtf((float)(cnt[i] + 1));
}

// ---------------------------------------------------------------- exclusive scan
#define SCAN_TPB 256
#define SCAN_VPT 4
#define SCAN_CHUNK (SCAN_TPB * SCAN_VPT)

__global__ void k_scan1(const int* __restrict__ in, int* __restrict__ out,
                        int* __restrict__ bsums, int n) {
    __shared__ int sh[SCAN_TPB];
    int t = threadIdx.x, b = blockIdx.x;
    int base = b * SCAN_CHUNK + t * SCAN_VPT;
    int v[SCAN_VPT]; int s = 0;
#pragma unroll
    for (int i = 0; i < SCAN_VPT; i++) {
        int idx = base + i;
        v[i] = (idx < n) ? in[idx] : 0;
        s += v[i];
    }
    sh[t] = s; __syncthreads();
    for (int off = 1; off < SCAN_TPB; off <<= 1) {
        int x = (t >= off) ? sh[t - off] : 0;
        __syncthreads();
        sh[t] += x;
        __syncthreads();
    }
    int run = (t > 0) ? sh[t - 1] : 0;
    if (t == SCAN_TPB - 1) bsums[b] = sh[t];
#pragma unroll
    for (int i = 0; i < SCAN_VPT; i++) {
        int idx = base + i;
        if (idx < n) out[idx] = run;
        run += v[i];
    }
}

__global__ void k_scan2(int* __restrict__ bsums, int nb, int* __restrict__ total) {
    __shared__ int sh[128];
    int t = threadIdx.x;
    int v = (t < nb) ? bsums[t] : 0;
    sh[t] = v; __syncthreads();
    for (int off = 1; off < 128; off <<= 1) {
        int x = (t >= off) ? sh[t - off] : 0;
        __syncthreads();
        sh[t] += x;
        __syncthreads();
    }
    if (t < nb) bsums[t] = sh[t] - v;
    if (t == 127) *total = sh[127];
}

__global__ void k_scan3(int* __restrict__ out, const int* __restrict__ bsums, int n) {
    int idx = blockIdx.x * blockDim.x + threadIdx.x;
    if (idx < n) out[idx] += bsums[idx / SCAN_CHUNK];
}

// ---------------------------------------------------------------- CSR fill
__global__ void k_fill(const int* __restrict__ src, const int* __restrict__ dst,
                       const int* __restrict__ offs, int* __restrict__ cursor,
                       const float* __restrict__ dinv,
                       int2* __restrict__ epack, int E) {
    int e = blockIdx.x * blockDim.x + threadIdx.x;
    if (e < E) {
        int s = src[e], d = dst[e];
        int p = offs[d] + atomicAdd(&cursor[d], 1);
        int2 r;
        r.x = s;
        r.y = __float_as_int(dinv[s] * dinv[d]);
        epack[p] = r;
    }
}

// ---------------------------------------------------------------- weight prep
// W[K][NC] fp32 -> f16 hi + f16 lo, SCALED x16 (lo stays out of subnormal
// flush), transposed [n][KPAD] k-contig, zero-padded k>=K.
__global__ void k_wprep16(const float* __restrict__ W, __half* __restrict__ Wh,
                          __half* __restrict__ Wl, int K, int KPAD, int NC) {
    int idx = blockIdx.x * blockDim.x + threadIdx.x;
    if (idx >= NC * KPAD) return;
    int n = idx / KPAD, k = idx - n * KPAD;
    float x = (k < K) ? W[k * NC + n] * 16.0f : 0.0f;
    __half h = __float2half_rn(x);
    __half l = __float2half_rn(x - __half2float(h));
    Wh[idx] = h; Wl[idx] = l;
}

// ---------------------------------------------------------------- fp32 -> fp16 convert (pad K->KPAD)
template <int K, int KPAD>
__global__ void k_tohalf(const float* __restrict__ in, __half* __restrict__ out, int rows) {
    const int cpr = KPAD >> 2;                 // 4-col chunks per row
    int idx = blockIdx.x * blockDim.x + threadIdx.x;
    if (idx >= rows * cpr) return;
    int r = idx / cpr, c4 = (idx - r * cpr) * 4;
    float4 v;
    if (c4 + 4 <= K) {
        v = *(const float4*)&in[(size_t)r * K + c4];
    } else {
        float* pv = (float*)&v;
#pragma unroll
        for (int i = 0; i < 4; i++)
            pv[i] = (c4 + i < K) ? in[(size_t)r * K + c4 + i] : 0.0f;
    }
    __half2 h0 = __floats2half2_rn(v.x, v.y);
    __half2 h1 = __floats2half2_rn(v.z, v.w);
    uint2 o; o.x = *(unsigned*)&h0; o.y = *(unsigned*)&h1;
    *(uint2*)&out[(size_t)r * KPAD + c4] = o;
}

// ---------------------------------------------------------------- register-resident MFMA GEMM
// C[M,NOUT] = X[M,KPAD](fp16) @ W (+bias), 2-term f16: x*w = x*wh + x*wl
// (W pre-scaled x16, unscaled in epilogue). NO LDS, NO BARRIERS:
//   A_mfma = W^T frags (lane (lm,q): Wt[col c0+mi*16+lm][ks*32+q*8], 16B) —
//            loaded ONCE per wave into registers (L2-hot, shared by all blocks)
//   B_mfma = X frags (lane: X[node n0+ni*16+lm][ks*32+q*8], 16B direct global)
//   D: node = lm (col idx), output cols = q*4+i (row idx) -> lane writes 4
//      consecutive cols -> coalesced 8B fp16 / 16B fp32 stores.
// One wave per (64-node tile x MI*16-col strip). MI=4: 64 cols, 2 strips.
template <int KPAD, int MI, int NOUT, bool BIAS, bool F32OUT>
__launch_bounds__(256)
__global__ void k_gemm_reg(const __half* __restrict__ X,
                           const __half* __restrict__ Wh, const __half* __restrict__ Wl,
                           const float* __restrict__ bias, void* __restrict__ Cout,
                           int M, int orow0) {
    constexpr int KS = KPAD / 32;
    const int tid  = threadIdx.x;
    const int wid  = tid >> 6, lane = tid & 63;
    const int lm   = lane & 15, q = lane >> 4;
    const int gw   = blockIdx.x * 4 + wid;
    const int NT   = (M + 63) >> 6;
    int tile, c0;
    if constexpr (MI == 4) { tile = gw >> 1; c0 = (gw & 1) * 64; }
    else                   { tile = gw;      c0 = 0; }
    if (tile >= NT) return;
    const int n0 = tile * 64;

    // W fragments, resident in registers
    half8 wh[MI][KS], wl[MI][KS];
#pragma unroll
    for (int mi = 0; mi < MI; mi++)
#pragma unroll
        for (int ks = 0; ks < KS; ks++) {
            const size_t b = (size_t)(c0 + mi * 16 + lm) * KPAD + ks * 32 + q * 8;
            wh[mi][ks] = *(const half8*)&Wh[b];
            wl[mi][ks] = *(const half8*)&Wl[b];
        }

    f32x4 acc[4][MI];
#pragma unroll
    for (int ni = 0; ni < 4; ni++)
#pragma unroll
        for (int mi = 0; mi < MI; mi++) acc[ni][mi] = (f32x4)0.0f;

#pragma unroll
    for (int ni = 0; ni < 4; ni++) {
        const int node = n0 + ni * 16 + lm;
        half8 xf[KS];
        if (node < M) {
#pragma unroll
            for (int ks = 0; ks < KS; ks++)
                xf[ks] = *(const half8*)&X[(size_t)node * KPAD + ks * 32 + q * 8];
        } else {
#pragma unroll
            for (int ks = 0; ks < KS; ks++)
#pragma unroll
                for (int j = 0; j < 8; j++) xf[ks][j] = (_Float16)0.0f;
        }
#pragma unroll
        for (int ks = 0; ks < KS; ks++)
#pragma unroll
            for (int mi = 0; mi < MI; mi++) {
                acc[ni][mi] = __builtin_amdgcn_mfma_f32_16x16x32_f16(wh[mi][ks], xf[ks], acc[ni][mi], 0, 0, 0);
                acc[ni][mi] = __builtin_amdgcn_mfma_f32_16x16x32_f16(wl[mi][ks], xf[ks], acc[ni][mi], 0, 0, 0);
            }
    }

    // epilogue: lane holds node=lm-based row, 4 consecutive cols q*4+i
#pragma unroll
    for (int ni = 0; ni < 4; ni++) {
        const int node = n0 + ni * 16 + lm;
        if (node >= M) continue;
#pragma unroll
        for (int mi = 0; mi < MI; mi++) {
            const int cb = c0 + mi * 16 + q * 4;
            float4 bv = BIAS ? *(const float4*)&bias[cb] : make_float4(0.f, 0.f, 0.f, 0.f);
            float v0 = fmaf(acc[ni][mi][0], 0.0625f, bv.x);
            float v1 = fmaf(acc[ni][mi][1], 0.0625f, bv.y);
            float v2 = fmaf(acc[ni][mi][2], 0.0625f, bv.z);
            float v3 = fmaf(acc[ni][mi][3], 0.0625f, bv.w);
            if constexpr (F32OUT) {
                *(float4*)((float*)Cout + (size_t)(orow0 + node) * NOUT + cb) =
                    make_float4(v0, v1, v2, v3);
            } else {
                __half2 h0 = __floats2half2_rn(v0, v1);
                __half2 h1 = __floats2half2_rn(v2, v3);
                uint2 o; o.x = *(unsigned*)&h0; o.y = *(unsigned*)&h1;
                *(uint2*)((__half*)Cout + (size_t)(orow0 + node) * NOUT + cb) = o;
            }
        }
    }
}

// ---------------------------------------------------------------- CSR gather + bias + ReLU
// One WAVE per node, FOUR edges in flight: 16 lanes x 16B (8 halves) per row.
// Edge records batch-loaded (one int2/lane), broadcast via shfl; 4 parity
// quarters combined with xor-shuffles (16, 32). fp32 accumulate, fp16 out.
__launch_bounds__(256)
__global__ void k_aggregate(const __half* __restrict__ y, const int* __restrict__ offs,
                            const int2* __restrict__ epack,
                            const float* __restrict__ dinv, const float* __restrict__ bias,
                            __half* __restrict__ out) {
    const int node = blockIdx.x * 4 + (threadIdx.x >> 6);
    const int l    = threadIdx.x & 63;
    const int g    = l >> 4;              // edge parity (0..3)
    const int s    = l & 15;              // 16B segment in row (16 x 16B = 256B)
    const int e0 = offs[node], e1 = offs[node + 1];
    const int deg = e1 - e0;

    const uint4* yv = (const uint4*)y;    // row stride = 16 uint4
    float acc[8];
#pragma unroll
    for (int t = 0; t < 8; t++) acc[t] = 0.0f;

    for (int base = 0; base < deg; base += 64) {
        const int m = min(64, deg - base);
        int2 pk = (l < m) ? epack[e0 + base + l] : make_int2(0, 0);
        const int quads = (m + 3) >> 2;
#pragma unroll 2
        for (int j = 0; j < quads; j++) {
            int idx  = 4 * j + g;
            int   sN = __shfl(pk.x, idx, 64);
            float w  = __int_as_float(__shfl(pk.y, idx, 64));
            if (idx < m) {
                uint4 v = yv[(size_t)sN * 16 + s];
                const __half2* hp = (const __half2*)&v;
#pragma unroll
                for (int t = 0; t < 4; t++) {
                    float2 f = __half22float2(hp[t]);
                    acc[2*t]     = fmaf(w, f.x, acc[2*t]);
                    acc[2*t + 1] = fmaf(w, f.y, acc[2*t + 1]);
                }
            }
        }
    }

    // combine 4 parity quarters: lanes {l, l^16, l^32, l^48}
#pragma unroll
    for (int t = 0; t < 8; t++) {
        acc[t] += __shfl_xor(acc[t], 16, 64);
        acc[t] += __shfl_xor(acc[t], 32, 64);
    }

    const float di2 = dinv[node] * dinv[node];
    uint4 sv = yv[(size_t)node * 16 + s];
    const __half2* sp = (const __half2*)&sv;
    float4 b0 = *(const float4*)&bias[8 * s];
    float4 b1 = *(const float4*)&bias[8 * s + 4];
    const float* bb = (const float*)&b0;   // b0,b1 contiguous on stack? use explicit
    float r[8];
#pragma unroll
    for (int t = 0; t < 4; t++) {
        float2 f = __half22float2(sp[t]);
        r[2*t]     = fmaf(f.x, di2, acc[2*t]);
        r[2*t + 1] = fmaf(f.y, di2, acc[2*t + 1]);
    }
    r[0] += b0.x; r[1] += b0.y; r[2] += b0.z; r[3] += b0.w;
    r[4] += b1.x; r[5] += b1.y; r[6] += b1.z; r[7] += b1.w;
    (void)bb;
    if (g == 0) {
        uint4 ov;
        __half2 o0 = __floats2half2_rn(fmaxf(r[0], 0.f), fmaxf(r[1], 0.f));
        __half2 o1 = __floats2half2_rn(fmaxf(r[2], 0.f), fmaxf(r[3], 0.f));
        __half2 o2 = __floats2half2_rn(fmaxf(r[4], 0.f), fmaxf(r[5], 0.f));
        __half2 o3 = __floats2half2_rn(fmaxf(r[6], 0.f), fmaxf(r[7], 0.f));
        ov.x = *(unsigned*)&o0; ov.y = *(unsigned*)&o1;
        ov.z = *(unsigned*)&o2; ov.w = *(unsigned*)&o3;
        ((uint4*)out)[(size_t)node * 16 + s] = ov;
    }
}

// ---------------------------------------------------------------- launch
extern "C" void kernel_launch(void* const* d_in, const int* in_sizes, int n_in,
                              void* d_out, int out_size, void* d_ws, size_t ws_size,
                              hipStream_t stream) {
    const float* user = (const float*)d_in[0];
    const float* prod = (const float*)d_in[1];
    const int*   eidx = (const int*)  d_in[2];
    const int*   edst = eidx + NE;
    const int*   esrc_in = eidx;
    const float* Wu = (const float*)d_in[3];
    const float* bu = (const float*)d_in[4];
    const float* Wp = (const float*)d_in[5];
    const float* bp = (const float*)d_in[6];
    const float* W1 = (const float*)d_in[7];
    const float* b1 = (const float*)d_in[8];
    const float* W2 = (const float*)d_in[9];
    const float* b2 = (const float*)d_in[10];
    const float* W3 = (const float*)d_in[11];
    const float* b3 = (const float*)d_in[12];
    const float* Wo = (const float*)d_in[13];
    const float* bo = (const float*)d_in[14];
    float* out = (float*)d_out;

    char* ws = (char*)d_ws;
    size_t p = 0;
    auto alloc = [&](size_t bytes) -> void* {
        void* r = ws + p;
        p += (bytes + 255) & ~(size_t)255;
        return r;
    };
    __half* xA   = (__half*)alloc((size_t)NN * H * 2);
    __half* xB   = (__half*)alloc((size_t)NN * H * 2);
    __half* xinU = (__half*)alloc((size_t)NU * 64 * 2);
    __half* xinP = (__half*)alloc((size_t)NP * 128 * 2);
    int*   cnt   = (int*)  alloc((size_t)NN * 4);
    int*   cursor= (int*)  alloc((size_t)NN * 4);
    int*   offs  = (int*)  alloc((size_t)(NN + 1) * 4);
    float* dinv  = (float*)alloc((size_t)NN * 4);
    int2*  epack = (int2*) alloc((size_t)NE * 8);
    int*   bsums = (int*)  alloc(128 * 4);
    __half* whU = (__half*)alloc(128 * 64 * 2);
    __half* wlU = (__half*)alloc(128 * 64 * 2);
    __half* whP = (__half*)alloc(128 * 128 * 2);
    __half* wlP = (__half*)alloc(128 * 128 * 2);
    __half* wh1 = (__half*)alloc(128 * 128 * 2);
    __half* wl1 = (__half*)alloc(128 * 128 * 2);
    __half* wh2 = (__half*)alloc(128 * 128 * 2);
    __half* wl2 = (__half*)alloc(128 * 128 * 2);
    __half* wh3 = (__half*)alloc(128 * 128 * 2);
    __half* wl3 = (__half*)alloc(128 * 128 * 2);
    __half* whO = (__half*)alloc(16 * 128 * 2);
    __half* wlO = (__half*)alloc(16 * 128 * 2);

    const int NBLK = (NN + SCAN_CHUNK - 1) / SCAN_CHUNK;

    // weight prep (split + transpose + x16 scale, once per call)
    k_wprep16<<<(128 *  64 + 255) / 256, 256, 0, stream>>>(Wu, whU, wlU,  64,  64, 128);
    k_wprep16<<<(128 * 128 + 255) / 256, 256, 0, stream>>>(Wp, whP, wlP, 100, 128, 128);
    k_wprep16<<<(128 * 128 + 255) / 256, 256, 0, stream>>>(W1, wh1, wl1, 128, 128, 128);
    k_wprep16<<<(128 * 128 + 255) / 256, 256, 0, stream>>>(W2, wh2, wl2, 128, 128, 128);
    k_wprep16<<<(128 * 128 + 255) / 256, 256, 0, stream>>>(W3, wh3, wl3, 128, 128, 128);
    k_wprep16<<<( 16 * 128 + 255) / 256, 256, 0, stream>>>(Wo, whO, wlO, 128, 128,  16);

    // input fp32 -> fp16 (pad prod K 100->128)
    k_tohalf< 64,  64><<<(NU * 16 + 255) / 256, 256, 0, stream>>>(user, xinU, NU);
    k_tohalf<100, 128><<<(NP * 32 + 255) / 256, 256, 0, stream>>>(prod, xinP, NP);

    // graph structure (once per call)
    k_init <<<(NN + 255) / 256, 256, 0, stream>>>(cnt, cursor, NN);
    k_count<<<(NE + 255) / 256, 256, 0, stream>>>(edst, cnt, NE);
    k_dinv <<<(NN + 255) / 256, 256, 0, stream>>>(cnt, dinv, NN);
    k_scan1<<<NBLK, SCAN_TPB, 0, stream>>>(cnt, offs, bsums, NN);
    k_scan2<<<1, 128, 0, stream>>>(bsums, NBLK, offs + NN);
    k_scan3<<<(NN + 255) / 256, 256, 0, stream>>>(offs, bsums, NN);
    k_fill <<<(NE + 255) / 256, 256, 0, stream>>>(esrc_in, edst, offs, cursor, dinv,
                                                  epack, NE);

    // input feature transforms -> xA (fp16)
    {
        int ntU = (NU + 63) / 64, blkU = (ntU * 2 + 3) / 4;
        k_gemm_reg< 64, 4, 128, true, false><<<blkU, 256, 0, stream>>>(xinU, whU, wlU, bu, xA, NU, 0);
        int ntP = (NP + 63) / 64, blkP = (ntP * 2 + 3) / 4;
        k_gemm_reg<128, 4, 128, true, false><<<blkP, 256, 0, stream>>>(xinP, whP, wlP, bp, xA, NP, NU);
    }

    const int ntN  = (NN + 63) / 64;
    const int blkG = (ntN * 2 + 3) / 4;   // MI=4 hidden gemms
    const int blkO = (ntN + 3) / 4;       // MI=1 head

    // layer 1
    k_gemm_reg<128, 4, 128, false, false><<<blkG, 256, 0, stream>>>(xA, wh1, wl1, nullptr, xB, NN, 0);
    k_aggregate<<<NN / 4, 256, 0, stream>>>(xB, offs, epack, dinv, b1, xA);
    // layer 2
    k_gemm_reg<128, 4, 128, false, false><<<blkG, 256, 0, stream>>>(xA, wh2, wl2, nullptr, xB, NN, 0);
    k_aggregate<<<NN / 4, 256, 0, stream>>>(xB, offs, epack, dinv, b2, xA);
    // layer 3
    k_gemm_reg<128, 4, 128, false, false><<<blkG, 256, 0, stream>>>(xA, wh3, wl3, nullptr, xB, NN, 0);
    k_aggregate<<<NN / 4, 256, 0, stream>>>(xB, offs, epack, dinv, b3, xA);

    // output head [NN,128] @ [128,16] + bo -> fp32 out
    k_gemm_reg<128, 1, 16, true, true><<<blkO, 256, 0, stream>>>(xA, whO, wlO, bo, out, NN, 0);
}

// Round 11
// 412.651 us; speedup vs baseline: 1.6255x; 1.0377x over previous
//
#include <hip/hip_runtime.h>
#include <hip/hip_fp16.h>

#define NU 50000
#define NP 50000
#define NN 100000
#define NE 600000
#define H  128
#define O  16

typedef __attribute__((ext_vector_type(8))) _Float16 half8;
typedef __attribute__((ext_vector_type(4))) float f32x4;

// ---------------------------------------------------------------- init / degree
__global__ void k_init(int* __restrict__ cnt, int* __restrict__ cursor, int n) {
    int i = blockIdx.x * blockDim.x + threadIdx.x;
    if (i < n) { cnt[i] = 0; cursor[i] = 0; }
}

__global__ void k_count(const int* __restrict__ dst, int* __restrict__ cnt, int E) {
    int e = blockIdx.x * blockDim.x + threadIdx.x;
    if (e < E) atomicAdd(&cnt[dst[e]], 1);
}

// ---------------------------------------------------------------- exclusive scan
#define SCAN_TPB 256
#define SCAN_VPT 4
#define SCAN_CHUNK (SCAN_TPB * SCAN_VPT)

// scan1 also emits dinv = rsqrt(cnt+1) (fused, saves a launch)
__global__ void k_scan1(const int* __restrict__ in, int* __restrict__ out,
                        int* __restrict__ bsums, float* __restrict__ dinv, int n) {
    __shared__ int sh[SCAN_TPB];
    int t = threadIdx.x, b = blockIdx.x;
    int base = b * SCAN_CHUNK + t * SCAN_VPT;
    int v[SCAN_VPT]; int s = 0;
#pragma unroll
    for (int i = 0; i < SCAN_VPT; i++) {
        int idx = base + i;
        v[i] = (idx < n) ? in[idx] : 0;
        if (idx < n) dinv[idx] = rsqrtf((float)(v[i] + 1));
        s += v[i];
    }
    sh[t] = s; __syncthreads();
    for (int off = 1; off < SCAN_TPB; off <<= 1) {
        int x = (t >= off) ? sh[t - off] : 0;
        __syncthreads();
        sh[t] += x;
        __syncthreads();
    }
    int run = (t > 0) ? sh[t - 1] : 0;
    if (t == SCAN_TPB - 1) bsums[b] = sh[t];
#pragma unroll
    for (int i = 0; i < SCAN_VPT; i++) {
        int idx = base + i;
        if (idx < n) out[idx] = run;
        run += v[i];
    }
}

__global__ void k_scan2(int* __restrict__ bsums, int nb, int* __restrict__ total) {
    __shared__ int sh[128];
    int t = threadIdx.x;
    int v = (t < nb) ? bsums[t] : 0;
    sh[t] = v; __syncthreads();
    for (int off = 1; off < 128; off <<= 1) {
        int x = (t >= off) ? sh[t - off] : 0;
        __syncthreads();
        sh[t] += x;
        __syncthreads();
    }
    if (t < nb) bsums[t] = sh[t] - v;
    if (t == 127) *total = sh[127];
}

__global__ void k_scan3(int* __restrict__ out, const int* __restrict__ bsums, int n) {
    int idx = blockIdx.x * blockDim.x + threadIdx.x;
    if (idx < n) out[idx] += bsums[idx / SCAN_CHUNK];
}

// ---------------------------------------------------------------- CSR fill
__global__ void k_fill(const int* __restrict__ src, const int* __restrict__ dst,
                       const int* __restrict__ offs, int* __restrict__ cursor,
                       const float* __restrict__ dinv,
                       int2* __restrict__ epack, int E) {
    int e = blockIdx.x * blockDim.x + threadIdx.x;
    if (e < E) {
        int s = src[e], d = dst[e];
        int p = offs[d] + atomicAdd(&cursor[d], 1);
        int2 r;
        r.x = s;
        r.y = __float_as_int(dinv[s] * dinv[d]);
        epack[p] = r;
    }
}

// ---------------------------------------------------------------- fused weight prep
// All 6 weight matrices in ONE launch. fp32 -> f16 hi + f16 lo, SCALED x16,
// transposed [n][KPAD] k-contig, zero-padded k>=K.
__global__ void k_wprep_all(const float* __restrict__ Wu, const float* __restrict__ Wp,
                            const float* __restrict__ W1, const float* __restrict__ W2,
                            const float* __restrict__ W3, const float* __restrict__ Wo,
                            __half* __restrict__ whU, __half* __restrict__ wlU,
                            __half* __restrict__ whP, __half* __restrict__ wlP,
                            __half* __restrict__ wh1, __half* __restrict__ wl1,
                            __half* __restrict__ wh2, __half* __restrict__ wl2,
                            __half* __restrict__ wh3, __half* __restrict__ wl3,
                            __half* __restrict__ whO, __half* __restrict__ wlO) {
    int idx = blockIdx.x * blockDim.x + threadIdx.x;
    const float* W; __half *Wh, *Wl; int K, KPAD, NC;
    if      (idx <  8192) {              W = Wu; Wh = whU; Wl = wlU; K =  64; KPAD =  64; NC = 128; }
    else if (idx < 24576) { idx -=  8192; W = Wp; Wh = whP; Wl = wlP; K = 100; KPAD = 128; NC = 128; }
    else if (idx < 40960) { idx -= 24576; W = W1; Wh = wh1; Wl = wl1; K = 128; KPAD = 128; NC = 128; }
    else if (idx < 57344) { idx -= 40960; W = W2; Wh = wh2; Wl = wl2; K = 128; KPAD = 128; NC = 128; }
    else if (idx < 73728) { idx -= 57344; W = W3; Wh = wh3; Wl = wl3; K = 128; KPAD = 128; NC = 128; }
    else if (idx < 75776) { idx -= 73728; W = Wo; Wh = whO; Wl = wlO; K = 128; KPAD = 128; NC =  16; }
    else return;
    int n = idx / KPAD, k = idx - n * KPAD;
    float x = (k < K) ? W[k * NC + n] * 16.0f : 0.0f;
    __half h = __float2half_rn(x);
    __half l = __float2half_rn(x - __half2float(h));
    Wh[idx] = h; Wl[idx] = l;
}

// ---------------------------------------------------------------- register-resident MFMA GEMM
// C[M,NOUT] = X[M,K] @ W (+bias), 2-term f16 (W pre-scaled x16, unscaled in
// epilogue). NO LDS, NO BARRIERS. A_mfma = W^T frags (register-resident),
// B_mfma = X frags loaded straight from global (fp16 direct 16B, or fp32
// 2x16B + inline cvt). D: node=lm, 4 consecutive cols=q*4+i -> coalesced.
template <typename AT, int K, int KPAD, int MI, int NOUT, bool BIAS, bool F32OUT>
__launch_bounds__(256)
__global__ void k_gemm_reg(const AT* __restrict__ X,
                           const __half* __restrict__ Wh, const __half* __restrict__ Wl,
                           const float* __restrict__ bias, void* __restrict__ Cout,
                           int M, int orow0) {
    constexpr int KS = KPAD / 32;
    const int tid  = threadIdx.x;
    const int wid  = tid >> 6, lane = tid & 63;
    const int lm   = lane & 15, q = lane >> 4;
    const int gw   = blockIdx.x * 4 + wid;
    const int NT   = (M + 63) >> 6;
    int tile, c0;
    if constexpr (MI == 4) { tile = gw >> 1; c0 = (gw & 1) * 64; }
    else                   { tile = gw;      c0 = 0; }
    if (tile >= NT) return;
    const int n0 = tile * 64;

    // W fragments, resident in registers (L2-hot; shared by all waves)
    half8 wh[MI][KS], wl[MI][KS];
#pragma unroll
    for (int mi = 0; mi < MI; mi++)
#pragma unroll
        for (int ks = 0; ks < KS; ks++) {
            const size_t b = (size_t)(c0 + mi * 16 + lm) * KPAD + ks * 32 + q * 8;
            wh[mi][ks] = *(const half8*)&Wh[b];
            wl[mi][ks] = *(const half8*)&Wl[b];
        }

    f32x4 acc[4][MI];
#pragma unroll
    for (int ni = 0; ni < 4; ni++)
#pragma unroll
        for (int mi = 0; mi < MI; mi++) acc[ni][mi] = (f32x4)0.0f;

#pragma unroll
    for (int ni = 0; ni < 4; ni++) {
        const int node = n0 + ni * 16 + lm;
        half8 xf[KS];
        if (node < M) {
            if constexpr (sizeof(AT) == 2) {        // fp16 input, K == KPAD
#pragma unroll
                for (int ks = 0; ks < KS; ks++)
                    xf[ks] = *(const half8*)((const __half*)X + (size_t)node * KPAD + ks * 32 + q * 8);
            } else {                                // fp32 input, inline convert
                const float* xp = (const float*)X + (size_t)node * K;
#pragma unroll
                for (int ks = 0; ks < KS; ks++) {
                    const int kb = ks * 32 + q * 8;
                    if (kb + 8 <= K) {
                        float4 v0 = *(const float4*)(xp + kb);
                        float4 v1 = *(const float4*)(xp + kb + 4);
                        xf[ks][0] = (_Float16)v0.x; xf[ks][1] = (_Float16)v0.y;
                        xf[ks][2] = (_Float16)v0.z; xf[ks][3] = (_Float16)v0.w;
                        xf[ks][4] = (_Float16)v1.x; xf[ks][5] = (_Float16)v1.y;
                        xf[ks][6] = (_Float16)v1.z; xf[ks][7] = (_Float16)v1.w;
                    } else {
#pragma unroll
                        for (int j = 0; j < 8; j++) {
                            int k = kb + j;
                            xf[ks][j] = (k < K) ? (_Float16)xp[k] : (_Float16)0.0f;
                        }
                    }
                }
            }
        } else {
#pragma unroll
            for (int ks = 0; ks < KS; ks++)
#pragma unroll
                for (int j = 0; j < 8; j++) xf[ks][j] = (_Float16)0.0f;
        }
#pragma unroll
        for (int ks = 0; ks < KS; ks++)
#pragma unroll
            for (int mi = 0; mi < MI; mi++) {
                acc[ni][mi] = __builtin_amdgcn_mfma_f32_16x16x32_f16(wh[mi][ks], xf[ks], acc[ni][mi], 0, 0, 0);
                acc[ni][mi] = __builtin_amdgcn_mfma_f32_16x16x32_f16(wl[mi][ks], xf[ks], acc[ni][mi], 0, 0, 0);
            }
    }

    // epilogue
#pragma unroll
    for (int ni = 0; ni < 4; ni++) {
        const int node = n0 + ni * 16 + lm;
        if (node >= M) continue;
#pragma unroll
        for (int mi = 0; mi < MI; mi++) {
            const int cb = c0 + mi * 16 + q * 4;
            float4 bv = BIAS ? *(const float4*)&bias[cb] : make_float4(0.f, 0.f, 0.f, 0.f);
            float v0 = fmaf(acc[ni][mi][0], 0.0625f, bv.x);
            float v1 = fmaf(acc[ni][mi][1], 0.0625f, bv.y);
            float v2 = fmaf(acc[ni][mi][2], 0.0625f, bv.z);
            float v3 = fmaf(acc[ni][mi][3], 0.0625f, bv.w);
            if constexpr (F32OUT) {
                *(float4*)((float*)Cout + (size_t)(orow0 + node) * NOUT + cb) =
                    make_float4(v0, v1, v2, v3);
            } else {
                __half2 h0 = __floats2half2_rn(v0, v1);
                __half2 h1 = __floats2half2_rn(v2, v3);
                uint2 o; o.x = *(unsigned*)&h0; o.y = *(unsigned*)&h1;
                *(uint2*)((__half*)Cout + (size_t)(orow0 + node) * NOUT + cb) = o;
            }
        }
    }
}

// ---------------------------------------------------------------- CSR gather + bias + ReLU
// One WAVE per node, FOUR edges in flight: 16 lanes x 16B per row. Inner loop
// written as fmaf((float)h16, w, acc) so LLVM emits v_fma_mix_f32 (fused
// f16-extend + fp32 FMA): halves inner-loop VALU vs cvt+fma.
__launch_bounds__(256)
__global__ void k_aggregate(const __half* __restrict__ y, const int* __restrict__ offs,
                            const int2* __restrict__ epack,
                            const float* __restrict__ dinv, const float* __restrict__ bias,
                            __half* __restrict__ out) {
    const int node = blockIdx.x * 4 + (threadIdx.x >> 6);
    const int l    = threadIdx.x & 63;
    const int g    = l >> 4;              // edge parity (0..3)
    const int s    = l & 15;              // 16B segment in row
    const int e0 = offs[node], e1 = offs[node + 1];
    const int deg = e1 - e0;

    const uint4* yv = (const uint4*)y;    // row stride = 16 uint4
    float acc[8];
#pragma unroll
    for (int t = 0; t < 8; t++) acc[t] = 0.0f;

    for (int base = 0; base < deg; base += 64) {
        const int m = min(64, deg - base);
        int2 pk = (l < m) ? epack[e0 + base + l] : make_int2(0, 0);
        const int quads = (m + 3) >> 2;
#pragma unroll 2
        for (int j = 0; j < quads; j++) {
            int idx  = 4 * j + g;
            int   sN = __shfl(pk.x, idx, 64);
            float w  = __int_as_float(__shfl(pk.y, idx, 64));
            if (idx < m) {
                uint4 v = yv[(size_t)sN * 16 + s];
                const _Float16* hv = (const _Float16*)&v;
#pragma unroll
                for (int t = 0; t < 8; t++)
                    acc[t] = fmaf((float)hv[t], w, acc[t]);   // v_fma_mix_f32
            }
        }
    }

    // combine 4 parity quarters: lanes {l, l^16, l^32, l^48}
#pragma unroll
    for (int t = 0; t < 8; t++) {
        acc[t] += __shfl_xor(acc[t], 16, 64);
        acc[t] += __shfl_xor(acc[t], 32, 64);
    }

    const float di2 = dinv[node] * dinv[node];
    uint4 sv = yv[(size_t)node * 16 + s];
    const _Float16* sp = (const _Float16*)&sv;
    float4 b0 = *(const float4*)&bias[8 * s];
    float4 b1 = *(const float4*)&bias[8 * s + 4];
    float r[8];
#pragma unroll
    for (int t = 0; t < 8; t++)
        r[t] = fmaf((float)sp[t], di2, acc[t]);
    r[0] += b0.x; r[1] += b0.y; r[2] += b0.z; r[3] += b0.w;
    r[4] += b1.x; r[5] += b1.y; r[6] += b1.z; r[7] += b1.w;
    if (g == 0) {
        uint4 ov;
        __half2 o0 = __floats2half2_rn(fmaxf(r[0], 0.f), fmaxf(r[1], 0.f));
        __half2 o1 = __floats2half2_rn(fmaxf(r[2], 0.f), fmaxf(r[3], 0.f));
        __half2 o2 = __floats2half2_rn(fmaxf(r[4], 0.f), fmaxf(r[5], 0.f));
        __half2 o3 = __floats2half2_rn(fmaxf(r[6], 0.f), fmaxf(r[7], 0.f));
        ov.x = *(unsigned*)&o0; ov.y = *(unsigned*)&o1;
        ov.z = *(unsigned*)&o2; ov.w = *(unsigned*)&o3;
        ((uint4*)out)[(size_t)node * 16 + s] = ov;
    }
}

// ---------------------------------------------------------------- launch
extern "C" void kernel_launch(void* const* d_in, const int* in_sizes, int n_in,
                              void* d_out, int out_size, void* d_ws, size_t ws_size,
                              hipStream_t stream) {
    const float* user = (const float*)d_in[0];
    const float* prod = (const float*)d_in[1];
    const int*   eidx = (const int*)  d_in[2];
    const int*   edst = eidx + NE;
    const int*   esrc_in = eidx;
    const float* Wu = (const float*)d_in[3];
    const float* bu = (const float*)d_in[4];
    const float* Wp = (const float*)d_in[5];
    const float* bp = (const float*)d_in[6];
    const float* W1 = (const float*)d_in[7];
    const float* b1 = (const float*)d_in[8];
    const float* W2 = (const float*)d_in[9];
    const float* b2 = (const float*)d_in[10];
    const float* W3 = (const float*)d_in[11];
    const float* b3 = (const float*)d_in[12];
    const float* Wo = (const float*)d_in[13];
    const float* bo = (const float*)d_in[14];
    float* out = (float*)d_out;

    char* ws = (char*)d_ws;
    size_t p = 0;
    auto alloc = [&](size_t bytes) -> void* {
        void* r = ws + p;
        p += (bytes + 255) & ~(size_t)255;
        return r;
    };
    __half* xA   = (__half*)alloc((size_t)NN * H * 2);
    __half* xB   = (__half*)alloc((size_t)NN * H * 2);
    int*   cnt   = (int*)  alloc((size_t)NN * 4);
    int*   cursor= (int*)  alloc((size_t)NN * 4);
    int*   offs  = (int*)  alloc((size_t)(NN + 1) * 4);
    float* dinv  = (float*)alloc((size_t)NN * 4);
    int2*  epack = (int2*) alloc((size_t)NE * 8);
    int*   bsums = (int*)  alloc(128 * 4);
    __half* whU = (__half*)alloc(128 * 64 * 2);
    __half* wlU = (__half*)alloc(128 * 64 * 2);
    __half* whP = (__half*)alloc(128 * 128 * 2);
    __half* wlP = (__half*)alloc(128 * 128 * 2);
    __half* wh1 = (__half*)alloc(128 * 128 * 2);
    __half* wl1 = (__half*)alloc(128 * 128 * 2);
    __half* wh2 = (__half*)alloc(128 * 128 * 2);
    __half* wl2 = (__half*)alloc(128 * 128 * 2);
    __half* wh3 = (__half*)alloc(128 * 128 * 2);
    __half* wl3 = (__half*)alloc(128 * 128 * 2);
    __half* whO = (__half*)alloc(16 * 128 * 2);
    __half* wlO = (__half*)alloc(16 * 128 * 2);

    const int NBLK = (NN + SCAN_CHUNK - 1) / SCAN_CHUNK;

    // fused weight prep (1 launch for all 6 matrices)
    k_wprep_all<<<(75776 + 255) / 256, 256, 0, stream>>>(
        Wu, Wp, W1, W2, W3, Wo,
        whU, wlU, whP, wlP, wh1, wl1, wh2, wl2, wh3, wl3, whO, wlO);

    // graph structure
    k_init <<<(NN + 255) / 256, 256, 0, stream>>>(cnt, cursor, NN);
    k_count<<<(NE + 255) / 256, 256, 0, stream>>>(edst, cnt, NE);
    k_scan1<<<NBLK, SCAN_TPB, 0, stream>>>(cnt, offs, bsums, dinv, NN);
    k_scan2<<<1, 128, 0, stream>>>(bsums, NBLK, offs + NN);
    k_scan3<<<(NN + 255) / 256, 256, 0, stream>>>(offs, bsums, NN);
    k_fill <<<(NE + 255) / 256, 256, 0, stream>>>(esrc_in, edst, offs, cursor, dinv,
                                                  epack, NE);

    // input feature transforms -> xA (fp16), fp32 inputs converted in-kernel
    {
        int ntU = (NU + 63) / 64, blkU = (ntU * 2 + 3) / 4;
        k_gemm_reg<float,  64,  64, 4, 128, true, false><<<blkU, 256, 0, stream>>>(user, whU, wlU, bu, xA, NU, 0);
        int ntP = (NP + 63) / 64, blkP = (ntP * 2 + 3) / 4;
        k_gemm_reg<float, 100, 128, 4, 128, true, false><<<blkP, 256, 0, stream>>>(prod, whP, wlP, bp, xA, NP, NU);
    }

    const int ntN  = (NN + 63) / 64;
    const int blkG = (ntN * 2 + 3) / 4;   // MI=4 hidden gemms
    const int blkO = (ntN + 3) / 4;       // MI=1 head

    // layer 1
    k_gemm_reg<__half, 128, 128, 4, 128, false, false><<<blkG, 256, 0, stream>>>(xA, wh1, wl1, nullptr, xB, NN, 0);
    k_aggregate<<<NN / 4, 256, 0, stream>>>(xB, offs, epack, dinv, b1, xA);
    // layer 2
    k_gemm_reg<__half, 128, 128, 4, 128, false, false><<<blkG, 256, 0, stream>>>(xA, wh2, wl2, nullptr, xB, NN, 0);
    k_aggregate<<<NN / 4, 256, 0, stream>>>(xB, offs, epack, dinv, b2, xA);
    // layer 3
    k_gemm_reg<__half, 128, 128, 4, 128, false, false><<<blkG, 256, 0, stream>>>(xA, wh3, wl3, nullptr, xB, NN, 0);
    k_aggregate<<<NN / 4, 256, 0, stream>>>(xB, offs, epack, dinv, b3, xA);

    // output head [NN,128] @ [128,16] + bo -> fp32 out
    k_gemm_reg<__half, 128, 128, 1, 16, true, true><<<blkO, 256, 0, stream>>>(xA, whO, wlO, bo, out, NN, 0);
}

// Round 12
// 410.551 us; speedup vs baseline: 1.6338x; 1.0051x over previous
//
#include <hip/hip_runtime.h>
#include <hip/hip_fp16.h>

#define NU 50000
#define NP 50000
#define NN 100000
#define NE 600000
#define H  128
#define O  16

typedef __attribute__((ext_vector_type(8))) _Float16 half8;
typedef __attribute__((ext_vector_type(4))) float f32x4;

// ---------------------------------------------------------------- init / degree
__global__ void k_init(int* __restrict__ cnt, int* __restrict__ cursor, int n) {
    int i = blockIdx.x * blockDim.x + threadIdx.x;
    if (i < n) { cnt[i] = 0; cursor[i] = 0; }
}

__global__ void k_count(const int* __restrict__ dst, int* __restrict__ cnt, int E) {
    int e = blockIdx.x * blockDim.x + threadIdx.x;
    if (e < E) atomicAdd(&cnt[dst[e]], 1);
}

// ---------------------------------------------------------------- exclusive scan
#define SCAN_TPB 256
#define SCAN_VPT 4
#define SCAN_CHUNK (SCAN_TPB * SCAN_VPT)

// scan1 also emits dinv = rsqrt(cnt+1) (fused)
__global__ void k_scan1(const int* __restrict__ in, int* __restrict__ out,
                        int* __restrict__ bsums, float* __restrict__ dinv, int n) {
    __shared__ int sh[SCAN_TPB];
    int t = threadIdx.x, b = blockIdx.x;
    int base = b * SCAN_CHUNK + t * SCAN_VPT;
    int v[SCAN_VPT]; int s = 0;
#pragma unroll
    for (int i = 0; i < SCAN_VPT; i++) {
        int idx = base + i;
        v[i] = (idx < n) ? in[idx] : 0;
        if (idx < n) dinv[idx] = rsqrtf((float)(v[i] + 1));
        s += v[i];
    }
    sh[t] = s; __syncthreads();
    for (int off = 1; off < SCAN_TPB; off <<= 1) {
        int x = (t >= off) ? sh[t - off] : 0;
        __syncthreads();
        sh[t] += x;
        __syncthreads();
    }
    int run = (t > 0) ? sh[t - 1] : 0;
    if (t == SCAN_TPB - 1) bsums[b] = sh[t];
#pragma unroll
    for (int i = 0; i < SCAN_VPT; i++) {
        int idx = base + i;
        if (idx < n) out[idx] = run;
        run += v[i];
    }
}

__global__ void k_scan2(int* __restrict__ bsums, int nb, int* __restrict__ total) {
    __shared__ int sh[128];
    int t = threadIdx.x;
    int v = (t < nb) ? bsums[t] : 0;
    sh[t] = v; __syncthreads();
    for (int off = 1; off < 128; off <<= 1) {
        int x = (t >= off) ? sh[t - off] : 0;
        __syncthreads();
        sh[t] += x;
        __syncthreads();
    }
    if (t < nb) bsums[t] = sh[t] - v;
    if (t == 127) *total = sh[127];
}

__global__ void k_scan3(int* __restrict__ out, const int* __restrict__ bsums, int n) {
    int idx = blockIdx.x * blockDim.x + threadIdx.x;
    if (idx < n) out[idx] += bsums[idx / SCAN_CHUNK];
}

// ---------------------------------------------------------------- CSR fill
__global__ void k_fill(const int* __restrict__ src, const int* __restrict__ dst,
                       const int* __restrict__ offs, int* __restrict__ cursor,
                       const float* __restrict__ dinv,
                       int2* __restrict__ epack, int E) {
    int e = blockIdx.x * blockDim.x + threadIdx.x;
    if (e < E) {
        int s = src[e], d = dst[e];
        int p = offs[d] + atomicAdd(&cursor[d], 1);
        int2 r;
        r.x = s;
        r.y = __float_as_int(dinv[s] * dinv[d]);
        epack[p] = r;
    }
}

// ---------------------------------------------------------------- fused weight prep
__global__ void k_wprep_all(const float* __restrict__ Wu, const float* __restrict__ Wp,
                            const float* __restrict__ W1, const float* __restrict__ W2,
                            const float* __restrict__ W3, const float* __restrict__ Wo,
                            __half* __restrict__ whU, __half* __restrict__ wlU,
                            __half* __restrict__ whP, __half* __restrict__ wlP,
                            __half* __restrict__ wh1, __half* __restrict__ wl1,
                            __half* __restrict__ wh2, __half* __restrict__ wl2,
                            __half* __restrict__ wh3, __half* __restrict__ wl3,
                            __half* __restrict__ whO, __half* __restrict__ wlO) {
    int idx = blockIdx.x * blockDim.x + threadIdx.x;
    const float* W; __half *Wh, *Wl; int K, KPAD, NC;
    if      (idx <  8192) {              W = Wu; Wh = whU; Wl = wlU; K =  64; KPAD =  64; NC = 128; }
    else if (idx < 24576) { idx -=  8192; W = Wp; Wh = whP; Wl = wlP; K = 100; KPAD = 128; NC = 128; }
    else if (idx < 40960) { idx -= 24576; W = W1; Wh = wh1; Wl = wl1; K = 128; KPAD = 128; NC = 128; }
    else if (idx < 57344) { idx -= 40960; W = W2; Wh = wh2; Wl = wl2; K = 128; KPAD = 128; NC = 128; }
    else if (idx < 73728) { idx -= 57344; W = W3; Wh = wh3; Wl = wl3; K = 128; KPAD = 128; NC = 128; }
    else if (idx < 75776) { idx -= 73728; W = Wo; Wh = whO; Wl = wlO; K = 128; KPAD = 128; NC =  16; }
    else return;
    int n = idx / KPAD, k = idx - n * KPAD;
    float x = (k < K) ? W[k * NC + n] * 16.0f : 0.0f;
    __half h = __float2half_rn(x);
    __half l = __float2half_rn(x - __half2float(h));
    Wh[idx] = h; Wl[idx] = l;
}

// ---------------------------------------------------------------- register-resident MFMA GEMM
// C[M,NOUT] = X[M,K] @ W (+bias), 2-term f16 (W pre-scaled x16, unscaled in
// epilogue). NO LDS, NO BARRIERS. A_mfma = W^T frags (register-resident),
// B_mfma = X frags straight from global. D: node=lm, cols q*4+i -> coalesced.
template <typename AT, int K, int KPAD, int MI, int NOUT, bool BIAS, bool F32OUT>
__launch_bounds__(256)
__global__ void k_gemm_reg(const AT* __restrict__ X,
                           const __half* __restrict__ Wh, const __half* __restrict__ Wl,
                           const float* __restrict__ bias, void* __restrict__ Cout,
                           int M, int orow0) {
    constexpr int KS = KPAD / 32;
    const int tid  = threadIdx.x;
    const int wid  = tid >> 6, lane = tid & 63;
    const int lm   = lane & 15, q = lane >> 4;
    const int gw   = blockIdx.x * 4 + wid;
    const int NT   = (M + 63) >> 6;
    int tile, c0;
    if constexpr (MI == 4) { tile = gw >> 1; c0 = (gw & 1) * 64; }
    else                   { tile = gw;      c0 = 0; }
    if (tile >= NT) return;
    const int n0 = tile * 64;

    half8 wh[MI][KS], wl[MI][KS];
#pragma unroll
    for (int mi = 0; mi < MI; mi++)
#pragma unroll
        for (int ks = 0; ks < KS; ks++) {
            const size_t b = (size_t)(c0 + mi * 16 + lm) * KPAD + ks * 32 + q * 8;
            wh[mi][ks] = *(const half8*)&Wh[b];
            wl[mi][ks] = *(const half8*)&Wl[b];
        }

    f32x4 acc[4][MI];
#pragma unroll
    for (int ni = 0; ni < 4; ni++)
#pragma unroll
        for (int mi = 0; mi < MI; mi++) acc[ni][mi] = (f32x4)0.0f;

#pragma unroll
    for (int ni = 0; ni < 4; ni++) {
        const int node = n0 + ni * 16 + lm;
        half8 xf[KS];
        if (node < M) {
            if constexpr (sizeof(AT) == 2) {
#pragma unroll
                for (int ks = 0; ks < KS; ks++)
                    xf[ks] = *(const half8*)((const __half*)X + (size_t)node * KPAD + ks * 32 + q * 8);
            } else {
                const float* xp = (const float*)X + (size_t)node * K;
#pragma unroll
                for (int ks = 0; ks < KS; ks++) {
                    const int kb = ks * 32 + q * 8;
                    if (kb + 8 <= K) {
                        float4 v0 = *(const float4*)(xp + kb);
                        float4 v1 = *(const float4*)(xp + kb + 4);
                        xf[ks][0] = (_Float16)v0.x; xf[ks][1] = (_Float16)v0.y;
                        xf[ks][2] = (_Float16)v0.z; xf[ks][3] = (_Float16)v0.w;
                        xf[ks][4] = (_Float16)v1.x; xf[ks][5] = (_Float16)v1.y;
                        xf[ks][6] = (_Float16)v1.z; xf[ks][7] = (_Float16)v1.w;
                    } else {
#pragma unroll
                        for (int j = 0; j < 8; j++) {
                            int k = kb + j;
                            xf[ks][j] = (k < K) ? (_Float16)xp[k] : (_Float16)0.0f;
                        }
                    }
                }
            }
        } else {
#pragma unroll
            for (int ks = 0; ks < KS; ks++)
#pragma unroll
                for (int j = 0; j < 8; j++) xf[ks][j] = (_Float16)0.0f;
        }
#pragma unroll
        for (int ks = 0; ks < KS; ks++)
#pragma unroll
            for (int mi = 0; mi < MI; mi++) {
                acc[ni][mi] = __builtin_amdgcn_mfma_f32_16x16x32_f16(wh[mi][ks], xf[ks], acc[ni][mi], 0, 0, 0);
                acc[ni][mi] = __builtin_amdgcn_mfma_f32_16x16x32_f16(wl[mi][ks], xf[ks], acc[ni][mi], 0, 0, 0);
            }
    }

#pragma unroll
    for (int ni = 0; ni < 4; ni++) {
        const int node = n0 + ni * 16 + lm;
        if (node >= M) continue;
#pragma unroll
        for (int mi = 0; mi < MI; mi++) {
            const int cb = c0 + mi * 16 + q * 4;
            float4 bv = BIAS ? *(const float4*)&bias[cb] : make_float4(0.f, 0.f, 0.f, 0.f);
            float v0 = fmaf(acc[ni][mi][0], 0.0625f, bv.x);
            float v1 = fmaf(acc[ni][mi][1], 0.0625f, bv.y);
            float v2 = fmaf(acc[ni][mi][2], 0.0625f, bv.z);
            float v3 = fmaf(acc[ni][mi][3], 0.0625f, bv.w);
            if constexpr (F32OUT) {
                *(float4*)((float*)Cout + (size_t)(orow0 + node) * NOUT + cb) =
                    make_float4(v0, v1, v2, v3);
            } else {
                __half2 h0 = __floats2half2_rn(v0, v1);
                __half2 h1 = __floats2half2_rn(v2, v3);
                uint2 o; o.x = *(unsigned*)&h0; o.y = *(unsigned*)&h1;
                *(uint2*)((__half*)Cout + (size_t)(orow0 + node) * NOUT + cb) = o;
            }
        }
    }
}

// ---------------------------------------------------------------- CSR gather + bias + ReLU
// One WAVE per node; lane owns features 2l..2l+1 (half2 = 4B; 64 lanes = full
// 256B row per load instruction). Edge records batch-loaded (one int2/lane),
// broadcast via v_readlane (wave-uniform index -> SALU, no ds_bpermute).
// FOUR independent accumulator chains merged in-register: zero cross-lane
// combine, zero LDS-pipe traffic, 4 gather loads in flight.
__launch_bounds__(256)
__global__ void k_aggregate(const __half* __restrict__ y, const int* __restrict__ offs,
                            const int2* __restrict__ epack,
                            const float* __restrict__ dinv, const float* __restrict__ bias,
                            __half* __restrict__ out) {
    const int node = blockIdx.x * 4 + (threadIdx.x >> 6);
    const int l    = threadIdx.x & 63;
    const int e0 = offs[node], e1 = offs[node + 1];
    const int deg = e1 - e0;

    const __half2* y2 = (const __half2*)y;    // row stride = 64 half2
    float a0x = 0.f, a0y = 0.f, a1x = 0.f, a1y = 0.f;
    float a2x = 0.f, a2y = 0.f, a3x = 0.f, a3y = 0.f;

    for (int base = 0; base < deg; base += 64) {
        const int m = min(64, deg - base);
        int2 pk = (l < m) ? epack[e0 + base + l] : make_int2(0, 0);
        int j = 0;
        for (; j + 4 <= m; j += 4) {
            int   s0 = __builtin_amdgcn_readlane(pk.x, j);
            float w0 = __int_as_float(__builtin_amdgcn_readlane(pk.y, j));
            int   s1 = __builtin_amdgcn_readlane(pk.x, j + 1);
            float w1 = __int_as_float(__builtin_amdgcn_readlane(pk.y, j + 1));
            int   s2 = __builtin_amdgcn_readlane(pk.x, j + 2);
            float w2 = __int_as_float(__builtin_amdgcn_readlane(pk.y, j + 2));
            int   s3 = __builtin_amdgcn_readlane(pk.x, j + 3);
            float w3 = __int_as_float(__builtin_amdgcn_readlane(pk.y, j + 3));
            __half2 v0 = y2[(size_t)s0 * 64 + l];
            __half2 v1 = y2[(size_t)s1 * 64 + l];
            __half2 v2 = y2[(size_t)s2 * 64 + l];
            __half2 v3 = y2[(size_t)s3 * 64 + l];
            const _Float16* h0 = (const _Float16*)&v0;
            const _Float16* h1 = (const _Float16*)&v1;
            const _Float16* h2 = (const _Float16*)&v2;
            const _Float16* h3 = (const _Float16*)&v3;
            a0x = fmaf((float)h0[0], w0, a0x); a0y = fmaf((float)h0[1], w0, a0y);
            a1x = fmaf((float)h1[0], w1, a1x); a1y = fmaf((float)h1[1], w1, a1y);
            a2x = fmaf((float)h2[0], w2, a2x); a2y = fmaf((float)h2[1], w2, a2y);
            a3x = fmaf((float)h3[0], w3, a3x); a3y = fmaf((float)h3[1], w3, a3y);
        }
        for (; j < m; j++) {
            int   s0 = __builtin_amdgcn_readlane(pk.x, j);
            float w0 = __int_as_float(__builtin_amdgcn_readlane(pk.y, j));
            __half2 v0 = y2[(size_t)s0 * 64 + l];
            const _Float16* h0 = (const _Float16*)&v0;
            a0x = fmaf((float)h0[0], w0, a0x);
            a0y = fmaf((float)h0[1], w0, a0y);
        }
    }

    float accx = (a0x + a1x) + (a2x + a3x);
    float accy = (a0y + a1y) + (a2y + a3y);

    const float di2 = dinv[node] * dinv[node];
    __half2 sv = y2[(size_t)node * 64 + l];
    const _Float16* sp = (const _Float16*)&sv;
    float2 bv = *(const float2*)&bias[2 * l];
    float rx = fmaf((float)sp[0], di2, accx) + bv.x;
    float ry = fmaf((float)sp[1], di2, accy) + bv.y;
    ((__half2*)out)[(size_t)node * 64 + l] =
        __floats2half2_rn(fmaxf(rx, 0.f), fmaxf(ry, 0.f));
}

// ---------------------------------------------------------------- launch
extern "C" void kernel_launch(void* const* d_in, const int* in_sizes, int n_in,
                              void* d_out, int out_size, void* d_ws, size_t ws_size,
                              hipStream_t stream) {
    const float* user = (const float*)d_in[0];
    const float* prod = (const float*)d_in[1];
    const int*   eidx = (const int*)  d_in[2];
    const int*   edst = eidx + NE;
    const int*   esrc_in = eidx;
    const float* Wu = (const float*)d_in[3];
    const float* bu = (const float*)d_in[4];
    const float* Wp = (const float*)d_in[5];
    const float* bp = (const float*)d_in[6];
    const float* W1 = (const float*)d_in[7];
    const float* b1 = (const float*)d_in[8];
    const float* W2 = (const float*)d_in[9];
    const float* b2 = (const float*)d_in[10];
    const float* W3 = (const float*)d_in[11];
    const float* b3 = (const float*)d_in[12];
    const float* Wo = (const float*)d_in[13];
    const float* bo = (const float*)d_in[14];
    float* out = (float*)d_out;

    char* ws = (char*)d_ws;
    size_t p = 0;
    auto alloc = [&](size_t bytes) -> void* {
        void* r = ws + p;
        p += (bytes + 255) & ~(size_t)255;
        return r;
    };
    __half* xA   = (__half*)alloc((size_t)NN * H * 2);
    __half* xB   = (__half*)alloc((size_t)NN * H * 2);
    int*   cnt   = (int*)  alloc((size_t)NN * 4);
    int*   cursor= (int*)  alloc((size_t)NN * 4);
    int*   offs  = (int*)  alloc((size_t)(NN + 1) * 4);
    float* dinv  = (float*)alloc((size_t)NN * 4);
    int2*  epack = (int2*) alloc((size_t)NE * 8);
    int*   bsums = (int*)  alloc(128 * 4);
    __half* whU = (__half*)alloc(128 * 64 * 2);
    __half* wlU = (__half*)alloc(128 * 64 * 2);
    __half* whP = (__half*)alloc(128 * 128 * 2);
    __half* wlP = (__half*)alloc(128 * 128 * 2);
    __half* wh1 = (__half*)alloc(128 * 128 * 2);
    __half* wl1 = (__half*)alloc(128 * 128 * 2);
    __half* wh2 = (__half*)alloc(128 * 128 * 2);
    __half* wl2 = (__half*)alloc(128 * 128 * 2);
    __half* wh3 = (__half*)alloc(128 * 128 * 2);
    __half* wl3 = (__half*)alloc(128 * 128 * 2);
    __half* whO = (__half*)alloc(16 * 128 * 2);
    __half* wlO = (__half*)alloc(16 * 128 * 2);

    const int NBLK = (NN + SCAN_CHUNK - 1) / SCAN_CHUNK;

    // fused weight prep (1 launch for all 6 matrices)
    k_wprep_all<<<(75776 + 255) / 256, 256, 0, stream>>>(
        Wu, Wp, W1, W2, W3, Wo,
        whU, wlU, whP, wlP, wh1, wl1, wh2, wl2, wh3, wl3, whO, wlO);

    // graph structure
    k_init <<<(NN + 255) / 256, 256, 0, stream>>>(cnt, cursor, NN);
    k_count<<<(NE + 255) / 256, 256, 0, stream>>>(edst, cnt, NE);
    k_scan1<<<NBLK, SCAN_TPB, 0, stream>>>(cnt, offs, bsums, dinv, NN);
    k_scan2<<<1, 128, 0, stream>>>(bsums, NBLK, offs + NN);
    k_scan3<<<(NN + 255) / 256, 256, 0, stream>>>(offs, bsums, NN);
    k_fill <<<(NE + 255) / 256, 256, 0, stream>>>(esrc_in, edst, offs, cursor, dinv,
                                                  epack, NE);

    // input feature transforms -> xA (fp16), fp32 inputs converted in-kernel
    {
        int ntU = (NU + 63) / 64, blkU = (ntU * 2 + 3) / 4;
        k_gemm_reg<float,  64,  64, 4, 128, true, false><<<blkU, 256, 0, stream>>>(user, whU, wlU, bu, xA, NU, 0);
        int ntP = (NP + 63) / 64, blkP = (ntP * 2 + 3) / 4;
        k_gemm_reg<float, 100, 128, 4, 128, true, false><<<blkP, 256, 0, stream>>>(prod, whP, wlP, bp, xA, NP, NU);
    }

    const int ntN  = (NN + 63) / 64;
    const int blkG = (ntN * 2 + 3) / 4;   // MI=4 hidden gemms
    const int blkO = (ntN + 3) / 4;       // MI=1 head

    // layer 1
    k_gemm_reg<__half, 128, 128, 4, 128, false, false><<<blkG, 256, 0, stream>>>(xA, wh1, wl1, nullptr, xB, NN, 0);
    k_aggregate<<<NN / 4, 256, 0, stream>>>(xB, offs, epack, dinv, b1, xA);
    // layer 2
    k_gemm_reg<__half, 128, 128, 4, 128, false, false><<<blkG, 256, 0, stream>>>(xA, wh2, wl2, nullptr, xB, NN, 0);
    k_aggregate<<<NN / 4, 256, 0, stream>>>(xB, offs, epack, dinv, b2, xA);
    // layer 3
    k_gemm_reg<__half, 128, 128, 4, 128, false, false><<<blkG, 256, 0, stream>>>(xA, wh3, wl3, nullptr, xB, NN, 0);
    k_aggregate<<<NN / 4, 256, 0, stream>>>(xB, offs, epack, dinv, b3, xA);

    // output head [NN,128] @ [128,16] + bo -> fp32 out
    k_gemm_reg<__half, 128, 128, 1, 16, true, true><<<blkO, 256, 0, stream>>>(xA, whO, wlO, bo, out, NN, 0);
}

// Round 13
// 405.794 us; speedup vs baseline: 1.6530x; 1.0117x over previous
//
#include <hip/hip_runtime.h>
#include <hip/hip_fp16.h>

#define NU 50000
#define NP 50000
#define NN 100000
#define NE 600000
#define H  128
#define O  16

typedef __attribute__((ext_vector_type(8))) _Float16 half8;
typedef __attribute__((ext_vector_type(4))) float f32x4;

// ---------------------------------------------------------------- init / degree
__global__ void k_init(int* __restrict__ cnt, int* __restrict__ cursor, int n) {
    int i = blockIdx.x * blockDim.x + threadIdx.x;
    if (i < n) { cnt[i] = 0; cursor[i] = 0; }
}

__global__ void k_count(const int* __restrict__ dst, int* __restrict__ cnt, int E) {
    int e = blockIdx.x * blockDim.x + threadIdx.x;
    if (e < E) atomicAdd(&cnt[dst[e]], 1);
}

// ---------------------------------------------------------------- exclusive scan
#define SCAN_TPB 256
#define SCAN_VPT 4
#define SCAN_CHUNK (SCAN_TPB * SCAN_VPT)

// scan1 also emits dinv = rsqrt(cnt+1) (fused)
__global__ void k_scan1(const int* __restrict__ in, int* __restrict__ out,
                        int* __restrict__ bsums, float* __restrict__ dinv, int n) {
    __shared__ int sh[SCAN_TPB];
    int t = threadIdx.x, b = blockIdx.x;
    int base = b * SCAN_CHUNK + t * SCAN_VPT;
    int v[SCAN_VPT]; int s = 0;
#pragma unroll
    for (int i = 0; i < SCAN_VPT; i++) {
        int idx = base + i;
        v[i] = (idx < n) ? in[idx] : 0;
        if (idx < n) dinv[idx] = rsqrtf((float)(v[i] + 1));
        s += v[i];
    }
    sh[t] = s; __syncthreads();
    for (int off = 1; off < SCAN_TPB; off <<= 1) {
        int x = (t >= off) ? sh[t - off] : 0;
        __syncthreads();
        sh[t] += x;
        __syncthreads();
    }
    int run = (t > 0) ? sh[t - 1] : 0;
    if (t == SCAN_TPB - 1) bsums[b] = sh[t];
#pragma unroll
    for (int i = 0; i < SCAN_VPT; i++) {
        int idx = base + i;
        if (idx < n) out[idx] = run;
        run += v[i];
    }
}

__global__ void k_scan2(int* __restrict__ bsums, int nb, int* __restrict__ total) {
    __shared__ int sh[128];
    int t = threadIdx.x;
    int v = (t < nb) ? bsums[t] : 0;
    sh[t] = v; __syncthreads();
    for (int off = 1; off < 128; off <<= 1) {
        int x = (t >= off) ? sh[t - off] : 0;
        __syncthreads();
        sh[t] += x;
        __syncthreads();
    }
    if (t < nb) bsums[t] = sh[t] - v;
    if (t == 127) *total = sh[127];
}

__global__ void k_scan3(int* __restrict__ out, const int* __restrict__ bsums, int n) {
    int idx = blockIdx.x * blockDim.x + threadIdx.x;
    if (idx < n) out[idx] += bsums[idx / SCAN_CHUNK];
}

// ---------------------------------------------------------------- CSR fill
__global__ void k_fill(const int* __restrict__ src, const int* __restrict__ dst,
                       const int* __restrict__ offs, int* __restrict__ cursor,
                       const float* __restrict__ dinv,
                       int2* __restrict__ epack, int E) {
    int e = blockIdx.x * blockDim.x + threadIdx.x;
    if (e < E) {
        int s = src[e], d = dst[e];
        int p = offs[d] + atomicAdd(&cursor[d], 1);
        int2 r;
        r.x = s;
        r.y = __float_as_int(dinv[s] * dinv[d]);
        epack[p] = r;
    }
}

// ---------------------------------------------------------------- fused weight prep
__global__ void k_wprep_all(const float* __restrict__ Wu, const float* __restrict__ Wp,
                            const float* __restrict__ W1, const float* __restrict__ W2,
                            const float* __restrict__ W3, const float* __restrict__ Wo,
                            __half* __restrict__ whU, __half* __restrict__ wlU,
                            __half* __restrict__ whP, __half* __restrict__ wlP,
                            __half* __restrict__ wh1, __half* __restrict__ wl1,
                            __half* __restrict__ wh2, __half* __restrict__ wl2,
                            __half* __restrict__ wh3, __half* __restrict__ wl3,
                            __half* __restrict__ whO, __half* __restrict__ wlO) {
    int idx = blockIdx.x * blockDim.x + threadIdx.x;
    const float* W; __half *Wh, *Wl; int K, KPAD, NC;
    if      (idx <  8192) {              W = Wu; Wh = whU; Wl = wlU; K =  64; KPAD =  64; NC = 128; }
    else if (idx < 24576) { idx -=  8192; W = Wp; Wh = whP; Wl = wlP; K = 100; KPAD = 128; NC = 128; }
    else if (idx < 40960) { idx -= 24576; W = W1; Wh = wh1; Wl = wl1; K = 128; KPAD = 128; NC = 128; }
    else if (idx < 57344) { idx -= 40960; W = W2; Wh = wh2; Wl = wl2; K = 128; KPAD = 128; NC = 128; }
    else if (idx < 73728) { idx -= 57344; W = W3; Wh = wh3; Wl = wl3; K = 128; KPAD = 128; NC = 128; }
    else if (idx < 75776) { idx -= 73728; W = Wo; Wh = whO; Wl = wlO; K = 128; KPAD = 128; NC =  16; }
    else return;
    int n = idx / KPAD, k = idx - n * KPAD;
    float x = (k < K) ? W[k * NC + n] * 16.0f : 0.0f;
    __half h = __float2half_rn(x);
    __half l = __float2half_rn(x - __half2float(h));
    Wh[idx] = h; Wl[idx] = l;
}

// ---------------------------------------------------------------- register-resident MFMA GEMM
// C[M,NOUT] = X[M,K] @ W (+bias), 2-term f16 (W pre-scaled x16, unscaled in
// epilogue). NO LDS, NO BARRIERS. A_mfma = W^T frags (register-resident),
// B_mfma = X frags straight from global. D: node=lm, cols q*4+i -> coalesced.
template <typename AT, int K, int KPAD, int MI, int NOUT, bool BIAS, bool F32OUT>
__launch_bounds__(256)
__global__ void k_gemm_reg(const AT* __restrict__ X,
                           const __half* __restrict__ Wh, const __half* __restrict__ Wl,
                           const float* __restrict__ bias, void* __restrict__ Cout,
                           int M, int orow0) {
    constexpr int KS = KPAD / 32;
    const int tid  = threadIdx.x;
    const int wid  = tid >> 6, lane = tid & 63;
    const int lm   = lane & 15, q = lane >> 4;
    const int gw   = blockIdx.x * 4 + wid;
    const int NT   = (M + 63) >> 6;
    int tile, c0;
    if constexpr (MI == 4) { tile = gw >> 1; c0 = (gw & 1) * 64; }
    else                   { tile = gw;      c0 = 0; }
    if (tile >= NT) return;
    const int n0 = tile * 64;

    half8 wh[MI][KS], wl[MI][KS];
#pragma unroll
    for (int mi = 0; mi < MI; mi++)
#pragma unroll
        for (int ks = 0; ks < KS; ks++) {
            const size_t b = (size_t)(c0 + mi * 16 + lm) * KPAD + ks * 32 + q * 8;
            wh[mi][ks] = *(const half8*)&Wh[b];
            wl[mi][ks] = *(const half8*)&Wl[b];
        }

    f32x4 acc[4][MI];
#pragma unroll
    for (int ni = 0; ni < 4; ni++)
#pragma unroll
        for (int mi = 0; mi < MI; mi++) acc[ni][mi] = (f32x4)0.0f;

#pragma unroll
    for (int ni = 0; ni < 4; ni++) {
        const int node = n0 + ni * 16 + lm;
        half8 xf[KS];
        if (node < M) {
            if constexpr (sizeof(AT) == 2) {
#pragma unroll
                for (int ks = 0; ks < KS; ks++)
                    xf[ks] = *(const half8*)((const __half*)X + (size_t)node * KPAD + ks * 32 + q * 8);
            } else {
                const float* xp = (const float*)X + (size_t)node * K;
#pragma unroll
                for (int ks = 0; ks < KS; ks++) {
                    const int kb = ks * 32 + q * 8;
                    if (kb + 8 <= K) {
                        float4 v0 = *(const float4*)(xp + kb);
                        float4 v1 = *(const float4*)(xp + kb + 4);
                        xf[ks][0] = (_Float16)v0.x; xf[ks][1] = (_Float16)v0.y;
                        xf[ks][2] = (_Float16)v0.z; xf[ks][3] = (_Float16)v0.w;
                        xf[ks][4] = (_Float16)v1.x; xf[ks][5] = (_Float16)v1.y;
                        xf[ks][6] = (_Float16)v1.z; xf[ks][7] = (_Float16)v1.w;
                    } else {
#pragma unroll
                        for (int j = 0; j < 8; j++) {
                            int k = kb + j;
                            xf[ks][j] = (k < K) ? (_Float16)xp[k] : (_Float16)0.0f;
                        }
                    }
                }
            }
        } else {
#pragma unroll
            for (int ks = 0; ks < KS; ks++)
#pragma unroll
                for (int j = 0; j < 8; j++) xf[ks][j] = (_Float16)0.0f;
        }
#pragma unroll
        for (int ks = 0; ks < KS; ks++)
#pragma unroll
            for (int mi = 0; mi < MI; mi++) {
                acc[ni][mi] = __builtin_amdgcn_mfma_f32_16x16x32_f16(wh[mi][ks], xf[ks], acc[ni][mi], 0, 0, 0);
                acc[ni][mi] = __builtin_amdgcn_mfma_f32_16x16x32_f16(wl[mi][ks], xf[ks], acc[ni][mi], 0, 0, 0);
            }
    }

#pragma unroll
    for (int ni = 0; ni < 4; ni++) {
        const int node = n0 + ni * 16 + lm;
        if (node >= M) continue;
#pragma unroll
        for (int mi = 0; mi < MI; mi++) {
            const int cb = c0 + mi * 16 + q * 4;
            float4 bv = BIAS ? *(const float4*)&bias[cb] : make_float4(0.f, 0.f, 0.f, 0.f);
            float v0 = fmaf(acc[ni][mi][0], 0.0625f, bv.x);
            float v1 = fmaf(acc[ni][mi][1], 0.0625f, bv.y);
            float v2 = fmaf(acc[ni][mi][2], 0.0625f, bv.z);
            float v3 = fmaf(acc[ni][mi][3], 0.0625f, bv.w);
            if constexpr (F32OUT) {
                *(float4*)((float*)Cout + (size_t)(orow0 + node) * NOUT + cb) =
                    make_float4(v0, v1, v2, v3);
            } else {
                __half2 h0 = __floats2half2_rn(v0, v1);
                __half2 h1 = __floats2half2_rn(v2, v3);
                uint2 o; o.x = *(unsigned*)&h0; o.y = *(unsigned*)&h1;
                *(uint2*)((__half*)Cout + (size_t)(orow0 + node) * NOUT + cb) = o;
            }
        }
    }
}

// ---------------------------------------------------------------- CSR gather + bias + ReLU
// One WAVE per node; lane owns features 2l..2l+1 (half2 = 4B; 64 lanes cover
// the full 256B row in one instruction). `node` forced wave-uniform via
// readfirstlane so offs[] / epack[] accesses are SCALAR loads (SMEM pipe,
// SGPR results): edge weight enters v_fma_mix as an SGPR operand, row base is
// SALU-computed saddr -> VALU per edge = exactly 2 fma_mix. Four independent
// accumulator chains keep 4 gathers in flight. Zero LDS, zero cross-lane ops.
__launch_bounds__(256)
__global__ void k_aggregate(const __half* __restrict__ y, const int* __restrict__ offs,
                            const int2* __restrict__ epack,
                            const float* __restrict__ dinv, const float* __restrict__ bias,
                            __half* __restrict__ out) {
    const int node = __builtin_amdgcn_readfirstlane(blockIdx.x * 4 + (threadIdx.x >> 6));
    const int l    = threadIdx.x & 63;
    const int e0 = offs[node], e1 = offs[node + 1];   // scalar loads

    const __half2* y2 = (const __half2*)y;            // row stride = 64 half2
    float a0x = 0.f, a0y = 0.f, a1x = 0.f, a1y = 0.f;
    float a2x = 0.f, a2y = 0.f, a3x = 0.f, a3y = 0.f;

    int e = e0;
    for (; e + 4 <= e1; e += 4) {
        int2 p0 = epack[e];                           // wave-uniform -> s_load
        int2 p1 = epack[e + 1];
        int2 p2 = epack[e + 2];
        int2 p3 = epack[e + 3];
        int   s0 = __builtin_amdgcn_readfirstlane(p0.x);
        int   s1 = __builtin_amdgcn_readfirstlane(p1.x);
        int   s2 = __builtin_amdgcn_readfirstlane(p2.x);
        int   s3 = __builtin_amdgcn_readfirstlane(p3.x);
        float w0 = __int_as_float(__builtin_amdgcn_readfirstlane(p0.y));
        float w1 = __int_as_float(__builtin_amdgcn_readfirstlane(p1.y));
        float w2 = __int_as_float(__builtin_amdgcn_readfirstlane(p2.y));
        float w3 = __int_as_float(__builtin_amdgcn_readfirstlane(p3.y));
        __half2 v0 = y2[(size_t)s0 * 64 + l];         // saddr + l*4
        __half2 v1 = y2[(size_t)s1 * 64 + l];
        __half2 v2 = y2[(size_t)s2 * 64 + l];
        __half2 v3 = y2[(size_t)s3 * 64 + l];
        const _Float16* h0 = (const _Float16*)&v0;
        const _Float16* h1 = (const _Float16*)&v1;
        const _Float16* h2 = (const _Float16*)&v2;
        const _Float16* h3 = (const _Float16*)&v3;
        a0x = fmaf((float)h0[0], w0, a0x); a0y = fmaf((float)h0[1], w0, a0y);
        a1x = fmaf((float)h1[0], w1, a1x); a1y = fmaf((float)h1[1], w1, a1y);
        a2x = fmaf((float)h2[0], w2, a2x); a2y = fmaf((float)h2[1], w2, a2y);
        a3x = fmaf((float)h3[0], w3, a3x); a3y = fmaf((float)h3[1], w3, a3y);
    }
    for (; e < e1; e++) {
        int2 p0 = epack[e];
        int   s0 = __builtin_amdgcn_readfirstlane(p0.x);
        float w0 = __int_as_float(__builtin_amdgcn_readfirstlane(p0.y));
        __half2 v0 = y2[(size_t)s0 * 64 + l];
        const _Float16* h0 = (const _Float16*)&v0;
        a0x = fmaf((float)h0[0], w0, a0x);
        a0y = fmaf((float)h0[1], w0, a0y);
    }

    float accx = (a0x + a1x) + (a2x + a3x);
    float accy = (a0y + a1y) + (a2y + a3y);

    const float di2 = dinv[node] * dinv[node];
    __half2 sv = y2[(size_t)node * 64 + l];
    const _Float16* sp = (const _Float16*)&sv;
    float2 bv = *(const float2*)&bias[2 * l];
    float rx = fmaf((float)sp[0], di2, accx) + bv.x;
    float ry = fmaf((float)sp[1], di2, accy) + bv.y;
    ((__half2*)out)[(size_t)node * 64 + l] =
        __floats2half2_rn(fmaxf(rx, 0.f), fmaxf(ry, 0.f));
}

// ---------------------------------------------------------------- launch
extern "C" void kernel_launch(void* const* d_in, const int* in_sizes, int n_in,
                              void* d_out, int out_size, void* d_ws, size_t ws_size,
                              hipStream_t stream) {
    const float* user = (const float*)d_in[0];
    const float* prod = (const float*)d_in[1];
    const int*   eidx = (const int*)  d_in[2];
    const int*   edst = eidx + NE;
    const int*   esrc_in = eidx;
    const float* Wu = (const float*)d_in[3];
    const float* bu = (const float*)d_in[4];
    const float* Wp = (const float*)d_in[5];
    const float* bp = (const float*)d_in[6];
    const float* W1 = (const float*)d_in[7];
    const float* b1 = (const float*)d_in[8];
    const float* W2 = (const float*)d_in[9];
    const float* b2 = (const float*)d_in[10];
    const float* W3 = (const float*)d_in[11];
    const float* b3 = (const float*)d_in[12];
    const float* Wo = (const float*)d_in[13];
    const float* bo = (const float*)d_in[14];
    float* out = (float*)d_out;

    char* ws = (char*)d_ws;
    size_t p = 0;
    auto alloc = [&](size_t bytes) -> void* {
        void* r = ws + p;
        p += (bytes + 255) & ~(size_t)255;
        return r;
    };
    __half* xA   = (__half*)alloc((size_t)NN * H * 2);
    __half* xB   = (__half*)alloc((size_t)NN * H * 2);
    int*   cnt   = (int*)  alloc((size_t)NN * 4);
    int*   cursor= (int*)  alloc((size_t)NN * 4);
    int*   offs  = (int*)  alloc((size_t)(NN + 1) * 4);
    float* dinv  = (float*)alloc((size_t)NN * 4);
    int2*  epack = (int2*) alloc((size_t)NE * 8);
    int*   bsums = (int*)  alloc(128 * 4);
    __half* whU = (__half*)alloc(128 * 64 * 2);
    __half* wlU = (__half*)alloc(128 * 64 * 2);
    __half* whP = (__half*)alloc(128 * 128 * 2);
    __half* wlP = (__half*)alloc(128 * 128 * 2);
    __half* wh1 = (__half*)alloc(128 * 128 * 2);
    __half* wl1 = (__half*)alloc(128 * 128 * 2);
    __half* wh2 = (__half*)alloc(128 * 128 * 2);
    __half* wl2 = (__half*)alloc(128 * 128 * 2);
    __half* wh3 = (__half*)alloc(128 * 128 * 2);
    __half* wl3 = (__half*)alloc(128 * 128 * 2);
    __half* whO = (__half*)alloc(16 * 128 * 2);
    __half* wlO = (__half*)alloc(16 * 128 * 2);

    const int NBLK = (NN + SCAN_CHUNK - 1) / SCAN_CHUNK;

    // fused weight prep (1 launch for all 6 matrices)
    k_wprep_all<<<(75776 + 255) / 256, 256, 0, stream>>>(
        Wu, Wp, W1, W2, W3, Wo,
        whU, wlU, whP, wlP, wh1, wl1, wh2, wl2, wh3, wl3, whO, wlO);

    // graph structure
    k_init <<<(NN + 255) / 256, 256, 0, stream>>>(cnt, cursor, NN);
    k_count<<<(NE + 255) / 256, 256, 0, stream>>>(edst, cnt, NE);
    k_scan1<<<NBLK, SCAN_TPB, 0, stream>>>(cnt, offs, bsums, dinv, NN);
    k_scan2<<<1, 128, 0, stream>>>(bsums, NBLK, offs + NN);
    k_scan3<<<(NN + 255) / 256, 256, 0, stream>>>(offs, bsums, NN);
    k_fill <<<(NE + 255) / 256, 256, 0, stream>>>(esrc_in, edst, offs, cursor, dinv,
                                                  epack, NE);

    // input feature transforms -> xA (fp16), fp32 inputs converted in-kernel
    {
        int ntU = (NU + 63) / 64, blkU = (ntU * 2 + 3) / 4;
        k_gemm_reg<float,  64,  64, 4, 128, true, false><<<blkU, 256, 0, stream>>>(user, whU, wlU, bu, xA, NU, 0);
        int ntP = (NP + 63) / 64, blkP = (ntP * 2 + 3) / 4;
        k_gemm_reg<float, 100, 128, 4, 128, true, false><<<blkP, 256, 0, stream>>>(prod, whP, wlP, bp, xA, NP, NU);
    }

    const int ntN  = (NN + 63) / 64;
    const int blkG = (ntN * 2 + 3) / 4;   // MI=4 hidden gemms
    const int blkO = (ntN + 3) / 4;       // MI=1 head

    // layer 1
    k_gemm_reg<__half, 128, 128, 4, 128, false, false><<<blkG, 256, 0, stream>>>(xA, wh1, wl1, nullptr, xB, NN, 0);
    k_aggregate<<<NN / 4, 256, 0, stream>>>(xB, offs, epack, dinv, b1, xA);
    // layer 2
    k_gemm_reg<__half, 128, 128, 4, 128, false, false><<<blkG, 256, 0, stream>>>(xA, wh2, wl2, nullptr, xB, NN, 0);
    k_aggregate<<<NN / 4, 256, 0, stream>>>(xB, offs, epack, dinv, b2, xA);
    // layer 3
    k_gemm_reg<__half, 128, 128, 4, 128, false, false><<<blkG, 256, 0, stream>>>(xA, wh3, wl3, nullptr, xB, NN, 0);
    k_aggregate<<<NN / 4, 256, 0, stream>>>(xB, offs, epack, dinv, b3, xA);

    // output head [NN,128] @ [128,16] + bo -> fp32 out
    k_gemm_reg<__half, 128, 128, 1, 16, true, true><<<blkO, 256, 0, stream>>>(xA, whO, wlO, bo, out, NN, 0);
}